// Round 2
// baseline (1607.991 us; speedup 1.0000x reference)
//
#include <hip/hip_runtime.h>
#include <math.h>

#define THRESH_C 0.05f
#define COEF_C   0.01f

typedef __bf16 bf16;
typedef __bf16 bf16x8 __attribute__((ext_vector_type(8)));
typedef __bf16 bf16x4 __attribute__((ext_vector_type(4)));
typedef float  f32x4  __attribute__((ext_vector_type(4)));

// async global->LDS, 16B per lane, dest = wave-uniform base + lane*16
__device__ __forceinline__ void ld16(void* lds_base, const void* g) {
    __builtin_amdgcn_global_load_lds(
        (const __attribute__((address_space(1))) void*)g,
        (__attribute__((address_space(3))) void*)lds_base,
        16, 0, 0);
}

// bijective XCD swizzle (m204): orig round-robins XCDs; result gives each XCD
// a contiguous chunk of the logical wg space -> consecutive logical blocks
// within a chunk share operand panels in that XCD's L2.
__device__ __forceinline__ int xcd_swz(int orig, int nwg) {
    int q = nwg >> 3, r = nwg & 7;
    int xcd = orig & 7, idx = orig >> 3;
    return (xcd < r ? xcd * (q + 1) : r * (q + 1) + (xcd - r) * q) + idx;
}

// ---------------- f32 -> split (hi+lo bf16) ----------------
__global__ __launch_bounds__(256) void k_f32_to_split(const float* __restrict__ in,
                                                      bf16* __restrict__ hi,
                                                      bf16* __restrict__ lo, long n) {
    long i = ((long)blockIdx.x * 256 + threadIdx.x) * 4;
    if (i >= n) return;
    float4 v = *(const float4*)(in + i);
    bf16x4 h, l;
    h[0] = (bf16)v.x; l[0] = (bf16)(v.x - (float)h[0]);
    h[1] = (bf16)v.y; l[1] = (bf16)(v.y - (float)h[1]);
    h[2] = (bf16)v.z; l[2] = (bf16)(v.z - (float)h[2]);
    h[3] = (bf16)v.w; l[3] = (bf16)(v.w - (float)h[3]);
    *(bf16x4*)(hi + i) = h;
    *(bf16x4*)(lo + i) = l;
}

// ---------------- merged 4-way f32 transpose -> split (z picks source) ----------------
__global__ __launch_bounds__(256) void k_transpose4_split(const float* __restrict__ w0,
                                                          const float* __restrict__ w1,
                                                          const float* __restrict__ w2,
                                                          const float* __restrict__ w3,
                                                          bf16* __restrict__ oh,
                                                          bf16* __restrict__ ol) {
    __shared__ float t[64][65];
    int z = blockIdx.z;
    const float* in = (z == 0) ? w0 : (z == 1) ? w1 : (z == 2) ? w2 : w3;
    bf16* ohz = oh + (long)z * 1048576;
    bf16* olz = ol + (long)z * 1048576;
    int r0 = blockIdx.y * 64, c0 = blockIdx.x * 64;
    for (int i = threadIdx.x; i < 4096; i += 256) {
        int r = i >> 6, c = i & 63;
        t[r][c] = in[(long)(r0 + r) * 1024 + (c0 + c)];
    }
    __syncthreads();
    for (int i = threadIdx.x; i < 4096; i += 256) {
        int c = i >> 6, r = i & 63;
        float v = t[r][c];
        bf16 h = (bf16)v;
        long o = (long)(c0 + c) * 1024 + (r0 + r);
        ohz[o] = h;
        olz[o] = (bf16)(v - (float)h);
    }
}

// ---------------- expert weight transpose to bf16 ----------------
__global__ __launch_bounds__(256) void k_transpose_ew(const float* __restrict__ in,
                                                      bf16* __restrict__ out,
                                                      int R, int C) {
    __shared__ bf16 t[64][65];
    const float* ib = in + (long)blockIdx.z * R * C;
    bf16* ob = out + (long)blockIdx.z * R * C;
    int r0 = blockIdx.y * 64, c0 = blockIdx.x * 64;
    for (int i = threadIdx.x; i < 4096; i += 256) {
        int r = i >> 6, c = i & 63;
        t[r][c] = (bf16)ib[(long)(r0 + r) * C + (c0 + c)];
    }
    __syncthreads();
    for (int i = threadIdx.x; i < 4096; i += 256) {
        int c = i >> 6, r = i & 63;
        ob[(long)(c0 + c) * R + (r0 + r)] = t[r][c];
    }
}

// ---------------- merged bias folds: y_z = b2_z + W_z @ b1_z ----------------
__global__ __launch_bounds__(256) void k_bias_fold4(const float* __restrict__ W_in,
                                                    const float* __restrict__ Wa,
                                                    const float* __restrict__ bq,
                                                    const float* __restrict__ bk,
                                                    const float* __restrict__ bv,
                                                    const float* __restrict__ b_out,
                                                    const float* __restrict__ b_in,
                                                    const float* __restrict__ ba,
                                                    float* __restrict__ y) {
    int z = blockIdx.y;
    const float* W  = (z < 3) ? (W_in + (long)z * 1048576) : Wa;
    const float* b1 = (z == 0) ? bq : (z == 1) ? bk : (z == 2) ? bv : b_out;
    const float* b2 = (z < 3) ? (b_in + z * 1024) : ba;
    int row = blockIdx.x * 4 + (threadIdx.x >> 6);
    int lane = threadIdx.x & 63;
    const float* wr = W + (long)row * 1024;
    float s = 0.f;
    for (int k = lane; k < 1024; k += 64) s += wr[k] * b1[k];
#pragma unroll
    for (int o = 32; o >= 1; o >>= 1) s += __shfl_xor(s, o);
    if (lane == 0) y[z * 1024 + row] = b2[row] + s;
}

// ---------------- high-precision split-bf16 GEMM ----------------
enum { HP_SPLIT = 0, HP_F32 = 1, HP_SPLIT_HEADS = 2 };

template<int MODE>
__global__ __launch_bounds__(256)
void gemm_hp(const bf16* __restrict__ Ah, const bf16* __restrict__ Al, int lda, long sAz,
             const bf16* __restrict__ Bh, const bf16* __restrict__ Bl, int ldb, long sBz,
             void* __restrict__ Chv, bf16* __restrict__ Cl, int ldc, long sCz,
             const float* __restrict__ bias, float alpha, int M, int N, int K) {
    __shared__ alignas(16) bf16 sAh[128 * 32];
    __shared__ alignas(16) bf16 sAl[128 * 32];
    __shared__ alignas(16) bf16 sBh[128 * 32];
    __shared__ alignas(16) bf16 sBl[128 * 32];
    const int bm = blockIdx.y, bn = blockIdx.x, z = blockIdx.z;
    const int tid  = threadIdx.x;
    const int lane = tid & 63, wave = tid >> 6;
    const int quad = lane >> 4, l16 = lane & 15;
    const int wr = wave >> 1, wc = wave & 1;
    const int sr = tid >> 2;
    const int sc = (tid & 3) * 8;

    int arow0 = min(bm * 128 + sr, M - 1);
    int arow1 = min(bm * 128 + sr + 64, M - 1);
    int brow0 = min(bn * 128 + sr, N - 1);
    int brow1 = min(bn * 128 + sr + 64, N - 1);

    const bf16* pAh0 = Ah + (long)z * sAz + (long)arow0 * lda + sc;
    const bf16* pAh1 = Ah + (long)z * sAz + (long)arow1 * lda + sc;
    const bf16* pAl0 = Al + (long)z * sAz + (long)arow0 * lda + sc;
    const bf16* pAl1 = Al + (long)z * sAz + (long)arow1 * lda + sc;
    const bf16* pBh0 = Bh + (long)z * sBz + (long)brow0 * ldb + sc;
    const bf16* pBh1 = Bh + (long)z * sBz + (long)brow1 * ldb + sc;
    const bf16* pBl0 = Bl + (long)z * sBz + (long)brow0 * ldb + sc;
    const bf16* pBl1 = Bl + (long)z * sBz + (long)brow1 * ldb + sc;
    const int wo = wave << 9;

    f32x4 acc[4][4];
#pragma unroll
    for (int i = 0; i < 4; i++)
#pragma unroll
        for (int j = 0; j < 4; j++) acc[i][j] = (f32x4){0.f, 0.f, 0.f, 0.f};

    for (int k0 = 0; k0 < K; k0 += 32) {
        __syncthreads();
        ld16(sAh + wo,        pAh0 + k0);
        ld16(sAh + 2048 + wo, pAh1 + k0);
        ld16(sAl + wo,        pAl0 + k0);
        ld16(sAl + 2048 + wo, pAl1 + k0);
        ld16(sBh + wo,        pBh0 + k0);
        ld16(sBh + 2048 + wo, pBh1 + k0);
        ld16(sBl + wo,        pBl0 + k0);
        ld16(sBl + 2048 + wo, pBl1 + k0);
        __syncthreads();
        bf16x8 ah[4], al[4], bh[4], bl[4];
#pragma unroll
        for (int i = 0; i < 4; i++) {
            int ro = (wr * 64 + i * 16 + l16) * 32 + quad * 8;
            ah[i] = *(const bf16x8*)&sAh[ro];
            al[i] = *(const bf16x8*)&sAl[ro];
        }
#pragma unroll
        for (int j = 0; j < 4; j++) {
            int ro = (wc * 64 + j * 16 + l16) * 32 + quad * 8;
            bh[j] = *(const bf16x8*)&sBh[ro];
            bl[j] = *(const bf16x8*)&sBl[ro];
        }
#pragma unroll
        for (int i = 0; i < 4; i++)
#pragma unroll
            for (int j = 0; j < 4; j++) {
                acc[i][j] = __builtin_amdgcn_mfma_f32_16x16x32_bf16(al[i], bh[j], acc[i][j], 0, 0, 0);
                acc[i][j] = __builtin_amdgcn_mfma_f32_16x16x32_bf16(ah[i], bl[j], acc[i][j], 0, 0, 0);
                acc[i][j] = __builtin_amdgcn_mfma_f32_16x16x32_bf16(ah[i], bh[j], acc[i][j], 0, 0, 0);
            }
    }

#pragma unroll
    for (int i = 0; i < 4; i++) {
        int mbase = bm * 128 + wr * 64 + i * 16 + quad * 4;
#pragma unroll
        for (int j = 0; j < 4; j++) {
            int n = bn * 128 + wc * 64 + j * 16 + l16;
            if (n < N) {
                float bv = bias ? bias[n] : 0.f;
#pragma unroll
                for (int r = 0; r < 4; r++) {
                    int m = mbase + r;
                    if (m < M) {
                        float v = alpha * acc[i][j][r] + bv;
                        if (MODE == HP_SPLIT) {
                            long cidx = (long)z * sCz + (long)m * ldc + n;
                            bf16 h = (bf16)v;
                            ((bf16*)Chv)[cidx] = h;
                            Cl[cidx] = (bf16)(v - (float)h);
                        } else if (MODE == HP_F32) {
                            long cidx = (long)z * sCz + (long)m * ldc + n;
                            ((float*)Chv)[cidx] = v;
                        } else {  // HP_SPLIT_HEADS: [slice=(b,h)][seq][64]
                            int slice = ((m >> 10) << 4) + (n >> 6);
                            long idx = (long)slice * 65536 + (long)(m & 1023) * 64 + (n & 63);
                            bf16 h = (bf16)v;
                            ((bf16*)Chv)[idx] = h;
                            Cl[idx] = (bf16)(v - (float)h);
                        }
                    }
                }
            }
        }
    }
}

// ---------------- PV GEMM: per-slice P[1024x1024] @ V^T[64x1024]^T, 128x64 tiles ----------------
__global__ __launch_bounds__(256)
void gemm_pv(const bf16* __restrict__ Ph, const bf16* __restrict__ Pl,
             const bf16* __restrict__ Vh, const bf16* __restrict__ Vl,
             bf16* __restrict__ Oh, bf16* __restrict__ Ol) {
    __shared__ alignas(16) bf16 sAh[128 * 32];
    __shared__ alignas(16) bf16 sAl[128 * 32];
    __shared__ alignas(16) bf16 sBh[64 * 32];
    __shared__ alignas(16) bf16 sBl[64 * 32];
    const int bm = blockIdx.x, z = blockIdx.y;
    const int tid = threadIdx.x, lane = tid & 63, wave = tid >> 6;
    const int quad = lane >> 4, l16 = lane & 15;
    const int wr = wave & 1, wc = wave >> 1;   // 2 waves in M, 2 in N(32 each)
    const int sr = tid >> 2, sc = (tid & 3) * 8;

    const bf16* pA0h = Ph + (long)z * 1048576 + (long)(bm * 128 + sr) * 1024 + sc;
    const bf16* pA1h = pA0h + 64 * 1024;
    const bf16* pA0l = Pl + (long)z * 1048576 + (long)(bm * 128 + sr) * 1024 + sc;
    const bf16* pA1l = pA0l + 64 * 1024;
    const bf16* pB0h = Vh + (long)z * 65536 + (long)sr * 1024 + sc;
    const bf16* pB0l = Vl + (long)z * 65536 + (long)sr * 1024 + sc;
    const int wo = wave << 9;

    f32x4 acc[4][2];
#pragma unroll
    for (int i = 0; i < 4; i++)
#pragma unroll
        for (int j = 0; j < 2; j++) acc[i][j] = (f32x4){0.f, 0.f, 0.f, 0.f};

    for (int k0 = 0; k0 < 1024; k0 += 32) {
        __syncthreads();
        ld16(sAh + wo,        pA0h + k0);
        ld16(sAh + 2048 + wo, pA1h + k0);
        ld16(sAl + wo,        pA0l + k0);
        ld16(sAl + 2048 + wo, pA1l + k0);
        ld16(sBh + wo, pB0h + k0);
        ld16(sBl + wo, pB0l + k0);
        __syncthreads();
        bf16x8 ah[4], al[4], bh[2], bl[2];
#pragma unroll
        for (int i = 0; i < 4; i++) {
            int ro = (wr * 64 + i * 16 + l16) * 32 + quad * 8;
            ah[i] = *(const bf16x8*)&sAh[ro];
            al[i] = *(const bf16x8*)&sAl[ro];
        }
#pragma unroll
        for (int j = 0; j < 2; j++) {
            int ro = (wc * 32 + j * 16 + l16) * 32 + quad * 8;
            bh[j] = *(const bf16x8*)&sBh[ro];
            bl[j] = *(const bf16x8*)&sBl[ro];
        }
#pragma unroll
        for (int i = 0; i < 4; i++)
#pragma unroll
            for (int j = 0; j < 2; j++) {
                acc[i][j] = __builtin_amdgcn_mfma_f32_16x16x32_bf16(al[i], bh[j], acc[i][j], 0, 0, 0);
                acc[i][j] = __builtin_amdgcn_mfma_f32_16x16x32_bf16(ah[i], bl[j], acc[i][j], 0, 0, 0);
                acc[i][j] = __builtin_amdgcn_mfma_f32_16x16x32_bf16(ah[i], bh[j], acc[i][j], 0, 0, 0);
            }
    }

#pragma unroll
    for (int i = 0; i < 4; i++) {
        int mbase = bm * 128 + wr * 64 + i * 16 + quad * 4;
#pragma unroll
        for (int j = 0; j < 2; j++) {
            int n = wc * 32 + j * 16 + l16;
#pragma unroll
            for (int r = 0; r < 4; r++) {
                int m = mbase + r;
                long idx = (long)z * 65536 + (long)m * 64 + n;
                float v = acc[i][j][r];
                bf16 h = (bf16)v;
                Oh[idx] = h;
                Ol[idx] = (bf16)(v - (float)h);
            }
        }
    }
}

// ---------------- MoE GEMM1 (compacted tile grid, GELU epilogue) ----------------
__global__ __launch_bounds__(256)
void gemm_moe1(const bf16* __restrict__ Ae, const bf16* __restrict__ ew1t,
               const float* __restrict__ eb1, bf16* __restrict__ Hp,
               const int* __restrict__ counts, const int* __restrict__ bases,
               const int* __restrict__ tiles, const int* __restrict__ ntile) {
    const int wg = xcd_swz(blockIdx.x, gridDim.x);
    const int tile = wg >> 5;         // 32 bn-tiles (N=4096)
    const int bn = wg & 31;
    if (tile >= ntile[0]) return;
    const int te = tiles[tile];
    const int e = te >> 16, bm = te & 0xffff;
    const int M = counts[e];
    const bf16* A = Ae + (long)bases[e] * 1024;
    const bf16* B = ew1t + (long)e * 4194304;
    bf16* C = Hp + (long)bases[e] * 4096;
    const float* bias = eb1 + e * 4096;

    __shared__ alignas(16) bf16 sA[128 * 32];
    __shared__ alignas(16) bf16 sB[128 * 32];
    const int tid  = threadIdx.x;
    const int lane = tid & 63, wave = tid >> 6;
    const int quad = lane >> 4, l16 = lane & 15;
    const int wr = wave >> 1, wc = wave & 1;
    const int sr = tid >> 2;
    const int sc = (tid & 3) * 8;

    int arow0 = min(bm * 128 + sr, M - 1);
    int arow1 = min(bm * 128 + sr + 64, M - 1);
    int brow0 = bn * 128 + sr;
    const bf16* pA0 = A + (long)arow0 * 1024 + sc;
    const bf16* pA1 = A + (long)arow1 * 1024 + sc;
    const bf16* pB0 = B + (long)brow0 * 1024 + sc;
    const bf16* pB1 = B + (long)(brow0 + 64) * 1024 + sc;
    const int wo = wave << 9;

    f32x4 acc[4][4];
#pragma unroll
    for (int i = 0; i < 4; i++)
#pragma unroll
        for (int j = 0; j < 4; j++) acc[i][j] = (f32x4){0.f, 0.f, 0.f, 0.f};

    for (int k0 = 0; k0 < 1024; k0 += 32) {
        __syncthreads();
        ld16(sA + wo,        pA0 + k0);
        ld16(sA + 2048 + wo, pA1 + k0);
        ld16(sB + wo,        pB0 + k0);
        ld16(sB + 2048 + wo, pB1 + k0);
        __syncthreads();
        bf16x8 af[4], bfr[4];
#pragma unroll
        for (int i = 0; i < 4; i++)
            af[i] = *(const bf16x8*)&sA[(wr * 64 + i * 16 + l16) * 32 + quad * 8];
#pragma unroll
        for (int j = 0; j < 4; j++)
            bfr[j] = *(const bf16x8*)&sB[(wc * 64 + j * 16 + l16) * 32 + quad * 8];
#pragma unroll
        for (int i = 0; i < 4; i++)
#pragma unroll
            for (int j = 0; j < 4; j++)
                acc[i][j] = __builtin_amdgcn_mfma_f32_16x16x32_bf16(af[i], bfr[j], acc[i][j], 0, 0, 0);
    }

#pragma unroll
    for (int i = 0; i < 4; i++) {
        int mbase = bm * 128 + wr * 64 + i * 16 + quad * 4;
#pragma unroll
        for (int j = 0; j < 4; j++) {
            int n = bn * 128 + wc * 64 + j * 16 + l16;
            float bv = bias[n];
#pragma unroll
            for (int r = 0; r < 4; r++) {
                int m = mbase + r;
                if (m < M) {
                    float v = acc[i][j][r] + bv;
                    float g = 0.5f * v * (1.f + erff(v * 0.70710678118654752f));
                    C[(long)m * 4096 + n] = (bf16)g;
                }
            }
        }
    }
}

// ---------------- MoE GEMM2 (compacted tile grid, full-K, packed fp32 output) ----------------
__global__ __launch_bounds__(256)
void gemm_moe2(const bf16* __restrict__ Hp, const bf16* __restrict__ ew2t,
               float* __restrict__ Y,
               const int* __restrict__ counts, const int* __restrict__ bases,
               const int* __restrict__ tiles, const int* __restrict__ ntile) {
    const int wg = xcd_swz(blockIdx.x, gridDim.x);
    const int tile = wg >> 3;         // 8 bn-tiles (N=1024)
    const int bn = wg & 7;
    if (tile >= ntile[0]) return;
    const int te = tiles[tile];
    const int e = te >> 16, bm = te & 0xffff;
    const int M = counts[e];
    const bf16* A = Hp + (long)bases[e] * 4096;
    const bf16* B = ew2t + (long)e * 4194304;
    float* C = Y + (long)bases[e] * 1024;

    __shared__ alignas(16) bf16 sA[128 * 32];
    __shared__ alignas(16) bf16 sB[128 * 32];
    const int tid  = threadIdx.x;
    const int lane = tid & 63, wave = tid >> 6;
    const int quad = lane >> 4, l16 = lane & 15;
    const int wr = wave >> 1, wc = wave & 1;
    const int sr = tid >> 2;
    const int sc = (tid & 3) * 8;

    int arow0 = min(bm * 128 + sr, M - 1);
    int arow1 = min(bm * 128 + sr + 64, M - 1);
    int brow0 = bn * 128 + sr;
    const bf16* pA0 = A + (long)arow0 * 4096 + sc;
    const bf16* pA1 = A + (long)arow1 * 4096 + sc;
    const bf16* pB0 = B + (long)brow0 * 4096 + sc;
    const bf16* pB1 = B + (long)(brow0 + 64) * 4096 + sc;
    const int wo = wave << 9;

    f32x4 acc[4][4];
#pragma unroll
    for (int i = 0; i < 4; i++)
#pragma unroll
        for (int j = 0; j < 4; j++) acc[i][j] = (f32x4){0.f, 0.f, 0.f, 0.f};

    for (int k0 = 0; k0 < 4096; k0 += 32) {
        __syncthreads();
        ld16(sA + wo,        pA0 + k0);
        ld16(sA + 2048 + wo, pA1 + k0);
        ld16(sB + wo,        pB0 + k0);
        ld16(sB + 2048 + wo, pB1 + k0);
        __syncthreads();
        bf16x8 af[4], bfr[4];
#pragma unroll
        for (int i = 0; i < 4; i++)
            af[i] = *(const bf16x8*)&sA[(wr * 64 + i * 16 + l16) * 32 + quad * 8];
#pragma unroll
        for (int j = 0; j < 4; j++)
            bfr[j] = *(const bf16x8*)&sB[(wc * 64 + j * 16 + l16) * 32 + quad * 8];
#pragma unroll
        for (int i = 0; i < 4; i++)
#pragma unroll
            for (int j = 0; j < 4; j++)
                acc[i][j] = __builtin_amdgcn_mfma_f32_16x16x32_bf16(af[i], bfr[j], acc[i][j], 0, 0, 0);
    }

#pragma unroll
    for (int i = 0; i < 4; i++) {
        int mbase = bm * 128 + wr * 64 + i * 16 + quad * 4;
#pragma unroll
        for (int j = 0; j < 4; j++) {
            int n = bn * 128 + wc * 64 + j * 16 + l16;
#pragma unroll
            for (int r = 0; r < 4; r++) {
                int m = mbase + r;
                if (m < M) C[(long)m * 1024 + n] = acc[i][j][r];
            }
        }
    }
}

// ---------------- per-slice V transpose ----------------
__global__ __launch_bounds__(256) void k_vsplit(const bf16* __restrict__ VH_h,
                                                const bf16* __restrict__ VH_l,
                                                bf16* __restrict__ VT_h,
                                                bf16* __restrict__ VT_l) {
    __shared__ bf16 th[64][65];
    __shared__ bf16 tl[64][65];
    int s = blockIdx.y, q0 = blockIdx.x * 64;
    int b = s >> 4, h = s & 15;
    long ibase = ((long)(b * 1024 + q0)) * 1024 + h * 64;
    for (int i = threadIdx.x; i < 4096; i += 256) {
        int q = i >> 6, d = i & 63;
        th[q][d] = VH_h[ibase + (long)q * 1024 + d];
        tl[q][d] = VH_l[ibase + (long)q * 1024 + d];
    }
    __syncthreads();
    long obase = (long)s * 65536 + q0;
    for (int i = threadIdx.x; i < 4096; i += 256) {
        int d = i >> 6, q = i & 63;
        VT_h[obase + (long)d * 1024 + q] = th[q][d];
        VT_l[obase + (long)d * 1024 + q] = tl[q][d];
    }
}

// ---------------- O reassembly ----------------
__global__ __launch_bounds__(256) void k_ocopy(const bf16* __restrict__ Op_h,
                                               const bf16* __restrict__ Op_l,
                                               bf16* __restrict__ O_h,
                                               bf16* __restrict__ O_l) {
    int t = blockIdx.x * 4 + (threadIdx.x >> 6);
    int lane = threadIdx.x & 63;
    int b = t >> 10, q = t & 1023;
    int h = lane >> 2, dd = (lane & 3) * 16;
    long src = ((long)(b * 16 + h)) * 65536 + (long)q * 64 + dd;
    long dst = (long)t * 1024 + h * 64 + dd;
    *(bf16x8*)(O_h + dst)     = *(const bf16x8*)(Op_h + src);
    *(bf16x8*)(O_h + dst + 8) = *(const bf16x8*)(Op_h + src + 8);
    *(bf16x8*)(O_l + dst)     = *(const bf16x8*)(Op_l + src);
    *(bf16x8*)(O_l + dst + 8) = *(const bf16x8*)(Op_l + src + 8);
}

// ---------------- gather expert rows (packed) ----------------
__global__ __launch_bounds__(256) void k_gather(const bf16* __restrict__ Xb,
                                                const int* __restrict__ tok,
                                                const int* __restrict__ counts,
                                                const int* __restrict__ bases,
                                                bf16* __restrict__ Ae) {
    int e = blockIdx.y;
    int cnt = counts[e];
    long base = bases[e];
    for (int i = blockIdx.x; i < cnt; i += gridDim.x) {
        int t = tok[e * 4096 + i];
        const bf16x4* src = (const bf16x4*)(Xb + (long)t * 1024);
        bf16x4* dst = (bf16x4*)(Ae + (base + i) * 1024);
        dst[threadIdx.x] = src[threadIdx.x];
    }
}

// ---------------- in-place softmax on split rows ----------------
__global__ __launch_bounds__(256) void k_softmax_ip(bf16* __restrict__ Sh,
                                                    bf16* __restrict__ Sl) {
    int row = blockIdx.x * 4 + (threadIdx.x >> 6);
    int lane = threadIdx.x & 63;
    long o = (long)row * 1024 + lane * 16;
    bf16x8 h0 = *(const bf16x8*)(Sh + o), h1 = *(const bf16x8*)(Sh + o + 8);
    bf16x8 l0 = *(const bf16x8*)(Sl + o), l1 = *(const bf16x8*)(Sl + o + 8);
    float v[16];
#pragma unroll
    for (int i = 0; i < 8; i++) {
        v[i] = (float)h0[i] + (float)l0[i];
        v[8 + i] = (float)h1[i] + (float)l1[i];
    }
    float mx = v[0];
#pragma unroll
    for (int i = 1; i < 16; i++) mx = fmaxf(mx, v[i]);
#pragma unroll
    for (int of = 32; of >= 1; of >>= 1) mx = fmaxf(mx, __shfl_xor(mx, of));
    float s = 0.f;
#pragma unroll
    for (int i = 0; i < 16; i++) { v[i] = expf(v[i] - mx); s += v[i]; }
#pragma unroll
    for (int of = 32; of >= 1; of >>= 1) s += __shfl_xor(s, of);
    float inv = 1.f / s;
#pragma unroll
    for (int i = 0; i < 8; i++) {
        float a = v[i] * inv;
        h0[i] = (bf16)a; l0[i] = (bf16)(a - (float)h0[i]);
        float b = v[8 + i] * inv;
        h1[i] = (bf16)b; l1[i] = (bf16)(b - (float)h1[i]);
    }
    *(bf16x8*)(Sh + o) = h0;  *(bf16x8*)(Sh + o + 8) = h1;
    *(bf16x8*)(Sl + o) = l0;  *(bf16x8*)(Sl + o + 8) = l1;
}

// ---------------- layernorm ----------------
__global__ __launch_bounds__(256) void k_ln(const float* __restrict__ xin,
                                            const float* __restrict__ resid,
                                            const float* __restrict__ g,
                                            const float* __restrict__ bb,
                                            float* __restrict__ outf,
                                            bf16* __restrict__ outb) {
    int row = blockIdx.x * 4 + (threadIdx.x >> 6);
    int lane = threadIdx.x & 63;
    long base = (long)row * 1024 + lane * 16;
    float v[16];
#pragma unroll
    for (int i = 0; i < 16; i += 4) {
        f32x4 a = *(const f32x4*)(xin + base + i);
        if (resid) { f32x4 r4 = *(const f32x4*)(resid + base + i); a += r4; }
        v[i] = a[0]; v[i + 1] = a[1]; v[i + 2] = a[2]; v[i + 3] = a[3];
    }
    float s = 0.f;
#pragma unroll
    for (int i = 0; i < 16; i++) s += v[i];
#pragma unroll
    for (int o = 32; o >= 1; o >>= 1) s += __shfl_xor(s, o);
    float mean = s * (1.f / 1024.f);
    float vs = 0.f;
#pragma unroll
    for (int i = 0; i < 16; i++) { float d = v[i] - mean; vs += d * d; }
#pragma unroll
    for (int o = 32; o >= 1; o >>= 1) vs += __shfl_xor(vs, o);
    float inv = 1.f / sqrtf(vs * (1.f / 1024.f) + 1e-5f);
    const float* gp = g + lane * 16;
    const float* bp = bb + lane * 16;
#pragma unroll
    for (int i = 0; i < 16; i++) {
        float o = (v[i] - mean) * inv * gp[i] + bp[i];
        if (outf) outf[base + i] = o;
        if (outb) outb[base + i] = (bf16)o;
    }
}

// ---------------- fused MoE combine + residual + LN2 ----------------
__global__ __launch_bounds__(256) void k_moe_ln(const float* __restrict__ Y,
                                                const int* __restrict__ pos,
                                                const float* __restrict__ combine,
                                                const float* __restrict__ eb2,
                                                const float* __restrict__ resid,
                                                const float* __restrict__ g,
                                                const float* __restrict__ bb,
                                                float* __restrict__ outf) {
    int row = blockIdx.x * 4 + (threadIdx.x >> 6);
    int lane = threadIdx.x & 63;
    long base = (long)row * 1024 + lane * 16;
    float v[16];
#pragma unroll
    for (int i = 0; i < 16; i += 4) {
        f32x4 a = *(const f32x4*)(resid + base + i);
        v[i] = a[0]; v[i + 1] = a[1]; v[i + 2] = a[2]; v[i + 3] = a[3];
    }
    for (int e = 0; e < 8; e++) {
        int p = pos[row * 8 + e];
        if (p >= 0) {
            float c = combine[row * 8 + e];
            const float* yr = Y + (long)p * 1024 + lane * 16;
            const float* br = eb2 + e * 1024 + lane * 16;
#pragma unroll
            for (int i = 0; i < 16; i += 4) {
                f32x4 y4 = *(const f32x4*)(yr + i);
                f32x4 b4 = *(const f32x4*)(br + i);
                v[i]     += c * (y4[0] + b4[0]);
                v[i + 1] += c * (y4[1] + b4[1]);
                v[i + 2] += c * (y4[2] + b4[2]);
                v[i + 3] += c * (y4[3] + b4[3]);
            }
        }
    }
    float s = 0.f;
#pragma unroll
    for (int i = 0; i < 16; i++) s += v[i];
#pragma unroll
    for (int o = 32; o >= 1; o >>= 1) s += __shfl_xor(s, o);
    float mean = s * (1.f / 1024.f);
    float vs = 0.f;
#pragma unroll
    for (int i = 0; i < 16; i++) { float d = v[i] - mean; vs += d * d; }
#pragma unroll
    for (int o = 32; o >= 1; o >>= 1) vs += __shfl_xor(vs, o);
    float inv = 1.f / sqrtf(vs * (1.f / 1024.f) + 1e-5f);
    const float* gp = g + lane * 16;
    const float* bp = bb + lane * 16;
#pragma unroll
    for (int i = 0; i < 16; i++)
        outf[base + i] = (v[i] - mean) * inv * gp[i] + bp[i];
}

// ---------------- gating (no routing atomics) ----------------
__global__ __launch_bounds__(256) void k_gate(const float* __restrict__ X,
                                              const float* __restrict__ Wg,
                                              float* __restrict__ combine,
                                              float* __restrict__ partials) {
    __shared__ float sm[16];
    if (threadIdx.x < 16) sm[threadIdx.x] = 0.f;
    __syncthreads();
    int t = blockIdx.x * 4 + (threadIdx.x >> 6);
    int lane = threadIdx.x & 63;
    const float* x = X + (long)t * 1024;
    float acc[8] = {0.f, 0.f, 0.f, 0.f, 0.f, 0.f, 0.f, 0.f};
    for (int i = lane; i < 1024; i += 64) {
        float xv = x[i];
        const float* w = Wg + i * 8;
#pragma unroll
        for (int e = 0; e < 8; e++) acc[e] += xv * w[e];
    }
#pragma unroll
    for (int e = 0; e < 8; e++)
#pragma unroll
        for (int o = 32; o >= 1; o >>= 1) acc[e] += __shfl_xor(acc[e], o);
    if (lane == 0) {
        float mx = acc[0];
#pragma unroll
        for (int e = 1; e < 8; e++) mx = fmaxf(mx, acc[e]);
        float p[8], s = 0.f;
#pragma unroll
        for (int e = 0; e < 8; e++) { p[e] = expf(acc[e] - mx); s += p[e]; }
        float invs = 1.f / s;
#pragma unroll
        for (int e = 0; e < 8; e++) p[e] *= invs;
        float b1 = -1.f, b2 = -1.f, b3 = -1.f; int i1 = 0, i2 = 0, i3 = 0;
#pragma unroll
        for (int e = 0; e < 8; e++) {
            float pe = p[e];
            if (pe > b1)      { b3 = b2; i3 = i2; b2 = b1; i2 = i1; b1 = pe; i1 = e; }
            else if (pe > b2) { b3 = b2; i3 = i2; b2 = pe; i2 = e; }
            else if (pe > b3) { b3 = pe; i3 = e; }
        }
        float c[8] = {0.f, 0.f, 0.f, 0.f, 0.f, 0.f, 0.f, 0.f};
        c[i1] = b1;
        if (b2 >= THRESH_C) c[i2] = b2;
        if (b3 >= THRESH_C) c[i3] = b3;
        float* co = combine + (long)t * 8;
#pragma unroll
        for (int e = 0; e < 8; e++) co[e] = c[e];
#pragma unroll
        for (int e = 0; e < 8; e++) {
            atomicAdd(&sm[e], p[e]);
            if (c[e] > 0.f) atomicAdd(&sm[8 + e], 1.f);
        }
    }
    __syncthreads();
    if (threadIdx.x < 16) partials[(long)blockIdx.x * 16 + threadIdx.x] = sm[threadIdx.x];
}

// ---------------- deterministic routing (single block, prefix sums + positions + tile list) ----------------
__global__ __launch_bounds__(256) void k_route(const float* __restrict__ combine,
                                               int* __restrict__ counts,
                                               int* __restrict__ bases,
                                               int* __restrict__ tok,
                                               int* __restrict__ pos,
                                               int* __restrict__ tiles,
                                               int* __restrict__ ntile) {
    __shared__ int scan[256];
    int tid = threadIdx.x;
    int mybase = 0;   // running global packed-row base, identical on all threads
    int nt = 0;       // tile count (tracked on tid 0)
    for (int e = 0; e < 8; e++) {
        int pred[16]; int cnt = 0;
#pragma unroll
        for (int j = 0; j < 16; j++) {
            int t = tid * 16 + j;
            pred[j] = combine[t * 8 + e] > 0.f ? 1 : 0;
            cnt += pred[j];
        }
        scan[tid] = cnt;
        __syncthreads();
        for (int off = 1; off < 256; off <<= 1) {
            int v = (tid >= off) ? scan[tid - off] : 0;
            __syncthreads();
            scan[tid] += v;
            __syncthreads();
        }
        int start = scan[tid] - cnt;
        int total = scan[255];
        int o = e * 4096 + start;
        int gp = mybase + start;
#pragma unroll
        for (int j = 0; j < 16; j++) {
            int t = tid * 16 + j;
            if (pred[j]) { tok[o++] = t; pos[t * 8 + e] = gp++; }
            else pos[t * 8 + e] = -1;
        }
        if (tid == 0) {
            counts[e] = total; bases[e] = mybase;
            int nte = (total + 127) >> 7;
            for (int b = 0; b < nte; b++) tiles[nt++] = (e << 16) | b;
        }
        mybase += total;
        __syncthreads();
    }
    if (tid == 0) ntile[0] = nt;
}

// ---------------- aux reduce ----------------
__global__ __launch_bounds__(256) void k_aux(const float* __restrict__ partials, int nblocks,
                                             float* __restrict__ auxout) {
    __shared__ float red[256];
    int tid = threadIdx.x;
    int e = tid & 15, grp = tid >> 4;
    float s = 0.f;
    for (int b = grp; b < nblocks; b += 16) s += partials[(long)b * 16 + e];
    red[tid] = s;
    __syncthreads();
    if (grp == 0) {
        float tot = 0.f;
        for (int g2 = 0; g2 < 16; g2++) tot += red[g2 * 16 + e];
        red[tid] = tot;
    }
    __syncthreads();
    if (tid == 0) {
        float s2 = 0.f;
        for (int e2 = 0; e2 < 8; e2++)
            s2 += (red[8 + e2] * (1.f / 4096.f)) * (red[e2] * (1.f / 4096.f));
        auxout[0] = COEF_C * 8.f * s2;
    }
}

// ---------------- host ----------------
extern "C" void kernel_launch(void* const* d_in, const int* in_sizes, int n_in,
                              void* d_out, int out_size, void* d_ws, size_t ws_size,
                              hipStream_t stream) {
    const float* query     = (const float*)d_in[0];
    const float* key_value = (const float*)d_in[1];
    const float* Wq   = (const float*)d_in[2];
    const float* bq   = (const float*)d_in[3];
    const float* Wk   = (const float*)d_in[4];
    const float* bk   = (const float*)d_in[5];
    const float* Wv   = (const float*)d_in[6];
    const float* bv   = (const float*)d_in[7];
    const float* W_in = (const float*)d_in[8];
    const float* b_in = (const float*)d_in[9];
    const float* W_out = (const float*)d_in[10];
    const float* b_out = (const float*)d_in[11];
    const float* Wa   = (const float*)d_in[12];
    const float* ba   = (const float*)d_in[13];
    const float* ln1_g = (const float*)d_in[14];
    const float* ln1_b = (const float*)d_in[15];
    const float* Wg   = (const float*)d_in[16];
    const float* ew1  = (const float*)d_in[17];
    const float* eb1  = (const float*)d_in[18];
    const float* ew2  = (const float*)d_in[19];
    const float* eb2  = (const float*)d_in[20];
    const float* ln2_g = (const float*)d_in[21];
    const float* ln2_b = (const float*)d_in[22];

    const size_t MBY = 1ull << 20;
    const long MB1 = 1024L * 1024L;
    char* ws = (char*)d_ws;

    // phase-aliased workspace map (peak ~345 MB)
    bf16* Sh   = (bf16*)(ws + 0 * MBY);      // attn: 64MB (32 slices split-hi)
    bf16* Sl   = (bf16*)(ws + 64 * MBY);     // attn: 64MB
    bf16* ew1t = (bf16*)(ws + 0 * MBY);      // MoE phase
    bf16* ew2t = (bf16*)(ws + 64 * MBY);
    // prep region [128,192): contiguous slice layouts for merged launches
    bf16* WAll_h = (bf16*)(ws + 128 * MBY);  // 8MB: Win(3) + Wa slices
    bf16* WAll_l = (bf16*)(ws + 136 * MBY);  // 8MB
    bf16* WT_h   = (bf16*)(ws + 144 * MBY);  // 8MB: WqT,WkT,WvT,WoT slices
    bf16* WT_l   = (bf16*)(ws + 152 * MBY);  // 8MB
    bf16* Xq_h  = (bf16*)(ws + 160 * MBY), *Xq_l  = (bf16*)(ws + 168 * MBY);
    bf16* Xkv_h = (bf16*)(ws + 176 * MBY), *Xkv_l = (bf16*)(ws + 184 * MBY);
    // attn-phase aliases
    bf16* O_h  = (bf16*)(ws + 160 * MBY), *O_l  = (bf16*)(ws + 168 * MBY);  // over dead Xq
    bf16* QHp_h = (bf16*)(ws + 192 * MBY), *QHp_l = (bf16*)(ws + 200 * MBY);
    bf16* KHp_h = (bf16*)(ws + 208 * MBY), *KHp_l = (bf16*)(ws + 216 * MBY);
    bf16* VH_h  = (bf16*)(ws + 224 * MBY), *VH_l  = (bf16*)(ws + 232 * MBY);
    bf16* VTp_h = (bf16*)(ws + 240 * MBY), *VTp_l = (bf16*)(ws + 248 * MBY);
    bf16* Op_h  = (bf16*)(ws + 256 * MBY), *Op_l  = (bf16*)(ws + 264 * MBY);
    float* Xf   = (float*)(ws + 256 * MBY);   // over dead Op
    float* Af   = (float*)(ws + 272 * MBY);
    // MoE phase
    bf16* Ae      = (bf16*)(ws + 128 * MBY);  // packed, worst 24MB
    bf16* Hp      = (bf16*)(ws + 152 * MBY);  // packed, worst 96MB (ends 248MBY)
    float* Yp     = (float*)(ws + 272 * MBY); // packed fp32 expert outputs, worst 48MB (ends 320MBY)
    bf16* Xb   = (bf16*)(ws + 320 * MBY);
    bf16* Weff_h = (bf16*)(ws + 328 * MBY);   // 8MB: Weq,Wek,Wev,Woa slices
    bf16* Weff_l = (bf16*)(ws + 336 * MBY);   // 8MB
    float* combine  = (float*)(ws + 344 * MBY);
    float* partials = (float*)(ws + 344 * MBY + 128 * 1024);
    float* beff     = (float*)(ws + 344 * MBY + 192 * 1024);  // 4x1024 (slot3 = b_oa)
    int*   counts   = (int*)  (ws + 344 * MBY + 212 * 1024);
    int*   bases    = (int*)  (ws + 344 * MBY + 213 * 1024);
    int*   tok      = (int*)  (ws + 344 * MBY + 214 * 1024);  // 128KB, ends at 342KB
    int*   pos      = (int*)  (ws + 344 * MBY + 342 * 1024);  // 128KB: [token][expert] -> packed row
    int*   tiles    = (int*)  (ws + 344 * MBY + 472 * 1024);  // <=104 packed (e<<16)|bm
    int*   ntile    = tiles + 128;

    dim3 blk(256);

    // ---- prep: conversions + splits (merged) ----
    k_f32_to_split<<<4096, blk, 0, stream>>>(query, Xq_h, Xq_l, 4L * MB1);
    k_f32_to_split<<<4096, blk, 0, stream>>>(key_value, Xkv_h, Xkv_l, 4L * MB1);
    k_f32_to_split<<<3072, blk, 0, stream>>>(W_in, WAll_h, WAll_l, 3L * MB1);
    k_f32_to_split<<<1024, blk, 0, stream>>>(Wa, WAll_h + 3 * MB1, WAll_l + 3 * MB1, MB1);
    k_transpose4_split<<<dim3(16, 16, 4), blk, 0, stream>>>(Wq, Wk, Wv, W_out, WT_h, WT_l);
    k_bias_fold4<<<dim3(256, 4), blk, 0, stream>>>(W_in, Wa, bq, bk, bv, b_out, b_in, ba, beff);

    // ---- weight folds: one z=4 launch ----
    gemm_hp<HP_SPLIT><<<dim3(8, 8, 4), blk, 0, stream>>>(
        WAll_h, WAll_l, 1024, MB1, WT_h, WT_l, 1024, MB1,
        Weff_h, Weff_l, 1024, MB1, nullptr, 1.f, 1024, 1024, 1024);

    // ---- projections: Q/K to head-split layout, V to token layout ----
    dim3 gP(8, 32, 1);
    gemm_hp<HP_SPLIT_HEADS><<<gP, blk, 0, stream>>>(Xq_h, Xq_l, 1024, 0, Weff_h, Weff_l, 1024, 0,
                                                    QHp_h, QHp_l, 0, 0, beff, 1.f, 4096, 1024, 1024);
    gemm_hp<HP_SPLIT_HEADS><<<gP, blk, 0, stream>>>(Xkv_h, Xkv_l, 1024, 0, Weff_h + MB1, Weff_l + MB1, 1024, 0,
                                                    KHp_h, KHp_l, 0, 0, beff + 1024, 1.f, 4096, 1024, 1024);
    gemm_hp<HP_SPLIT><<<gP, blk, 0, stream>>>(Xkv_h, Xkv_l, 1024, 0, Weff_h + 2 * MB1, Weff_l + 2 * MB1, 1024, 0,
                                              VH_h, VH_l, 1024, 0, beff + 2048, 1.f, 4096, 1024, 1024);
    k_vsplit<<<dim3(16, 64), blk, 0, stream>>>(VH_h, VH_l, VTp_h, VTp_l);

    // ---- attention: 2 halves of 32 (b,h) slices ----
    for (int half = 0; half < 2; half++) {
        long so = (long)half * 32 * 65536;
        gemm_hp<HP_SPLIT><<<dim3(8, 8, 32), blk, 0, stream>>>(
            QHp_h + so, QHp_l + so, 64, 65536,
            KHp_h + so, KHp_l + so, 64, 65536,
            Sh, Sl, 1024, MB1, nullptr, 0.125f, 1024, 1024, 64);
        k_softmax_ip<<<8192, blk, 0, stream>>>(Sh, Sl);
        gemm_pv<<<dim3(8, 32), blk, 0, stream>>>(Sh, Sl, VTp_h + so, VTp_l + so,
                                                 Op_h + so, Op_l + so);
    }
    k_ocopy<<<1024, blk, 0, stream>>>(Op_h, Op_l, O_h, O_l);

    // ---- out-proj+adapter (folded) + LN1 + gate + route ----
    gemm_hp<HP_F32><<<gP, blk, 0, stream>>>(O_h, O_l, 1024, 0, Weff_h + 3 * MB1, Weff_l + 3 * MB1, 1024, 0,
                                            Af, nullptr, 1024, 0, beff + 3072, 1.f, 4096, 1024, 1024);
    k_ln<<<1024, blk, 0, stream>>>(Af, query, ln1_g, ln1_b, Xf, Xb);
    k_gate<<<1024, blk, 0, stream>>>(Xf, Wg, combine, partials);
    k_route<<<1, blk, 0, stream>>>(combine, counts, bases, tok, pos, tiles, ntile);
    k_gather<<<dim3(512, 8), blk, 0, stream>>>(Xb, tok, counts, bases, Ae);

    // ---- expert weight transposes ----
    k_transpose_ew<<<dim3(64, 16, 8), blk, 0, stream>>>(ew1, ew1t, 1024, 4096);
    k_transpose_ew<<<dim3(16, 64, 8), blk, 0, stream>>>(ew2, ew2t, 4096, 1024);

    // ---- batched routed MoE: compacted tile grids (tile-major, XCD-chunked) ----
    gemm_moe1<<<dim3(104 * 32), blk, 0, stream>>>(Ae, ew1t, eb1, Hp, counts, bases, tiles, ntile);
    gemm_moe2<<<dim3(104 * 8), blk, 0, stream>>>(Hp, ew2t, Yp, counts, bases, tiles, ntile);

    // ---- fused MoE combine + residual + LN2, then aux ----
    k_moe_ln<<<1024, blk, 0, stream>>>(Yp, pos, combine, eb2, Xf, ln2_g, ln2_b, (float*)d_out);
    k_aux<<<1, blk, 0, stream>>>(partials, 1024, (float*)d_out + (out_size - 1));
}

// Round 5
// 1551.831 us; speedup vs baseline: 1.0362x; 1.0362x over previous
//
#include <hip/hip_runtime.h>
#include <math.h>

#define THRESH_C 0.05f
#define COEF_C   0.01f

typedef __bf16 bf16;
typedef __bf16 bf16x8 __attribute__((ext_vector_type(8)));
typedef __bf16 bf16x4 __attribute__((ext_vector_type(4)));
typedef float  f32x4  __attribute__((ext_vector_type(4)));

// async global->LDS, 16B per lane, dest = wave-uniform base + lane*16
__device__ __forceinline__ void ld16(void* lds_base, const void* g) {
    __builtin_amdgcn_global_load_lds(
        (const __attribute__((address_space(1))) void*)g,
        (__attribute__((address_space(3))) void*)lds_base,
        16, 0, 0);
}

// bijective XCD swizzle (m204)
__device__ __forceinline__ int xcd_swz(int orig, int nwg) {
    int q = nwg >> 3, r = nwg & 7;
    int xcd = orig & 7, idx = orig >> 3;
    return (xcd < r ? xcd * (q + 1) : r * (q + 1) + (xcd - r) * q) + idx;
}

// ---------------- f32 -> split (hi+lo bf16) ----------------
__global__ __launch_bounds__(256) void k_f32_to_split(const float* __restrict__ in,
                                                      bf16* __restrict__ hi,
                                                      bf16* __restrict__ lo, long n) {
    long i = ((long)blockIdx.x * 256 + threadIdx.x) * 4;
    if (i >= n) return;
    float4 v = *(const float4*)(in + i);
    bf16x4 h, l;
    h[0] = (bf16)v.x; l[0] = (bf16)(v.x - (float)h[0]);
    h[1] = (bf16)v.y; l[1] = (bf16)(v.y - (float)h[1]);
    h[2] = (bf16)v.z; l[2] = (bf16)(v.z - (float)h[2]);
    h[3] = (bf16)v.w; l[3] = (bf16)(v.w - (float)h[3]);
    *(bf16x4*)(hi + i) = h;
    *(bf16x4*)(lo + i) = l;
}

// ---------------- merged 4-way f32 transpose -> split ----------------
__global__ __launch_bounds__(256) void k_transpose4_split(const float* __restrict__ w0,
                                                          const float* __restrict__ w1,
                                                          const float* __restrict__ w2,
                                                          const float* __restrict__ w3,
                                                          bf16* __restrict__ oh,
                                                          bf16* __restrict__ ol) {
    __shared__ float t[64][65];
    int z = blockIdx.z;
    const float* in = (z == 0) ? w0 : (z == 1) ? w1 : (z == 2) ? w2 : w3;
    bf16* ohz = oh + (long)z * 1048576;
    bf16* olz = ol + (long)z * 1048576;
    int r0 = blockIdx.y * 64, c0 = blockIdx.x * 64;
    for (int i = threadIdx.x; i < 4096; i += 256) {
        int r = i >> 6, c = i & 63;
        t[r][c] = in[(long)(r0 + r) * 1024 + (c0 + c)];
    }
    __syncthreads();
    for (int i = threadIdx.x; i < 4096; i += 256) {
        int c = i >> 6, r = i & 63;
        float v = t[r][c];
        bf16 h = (bf16)v;
        long o = (long)(c0 + c) * 1024 + (r0 + r);
        ohz[o] = h;
        olz[o] = (bf16)(v - (float)h);
    }
}

// ---------------- expert weight transpose to bf16 ----------------
__global__ __launch_bounds__(256) void k_transpose_ew(const float* __restrict__ in,
                                                      bf16* __restrict__ out,
                                                      int R, int C) {
    __shared__ bf16 t[64][65];
    const float* ib = in + (long)blockIdx.z * R * C;
    bf16* ob = out + (long)blockIdx.z * R * C;
    int r0 = blockIdx.y * 64, c0 = blockIdx.x * 64;
    for (int i = threadIdx.x; i < 4096; i += 256) {
        int r = i >> 6, c = i & 63;
        t[r][c] = (bf16)ib[(long)(r0 + r) * C + (c0 + c)];
    }
    __syncthreads();
    for (int i = threadIdx.x; i < 4096; i += 256) {
        int c = i >> 6, r = i & 63;
        ob[(long)(c0 + c) * R + (r0 + r)] = t[r][c];
    }
}

// ---------------- merged bias folds: y_z = b2_z + W_z @ b1_z ----------------
__global__ __launch_bounds__(256) void k_bias_fold4(const float* __restrict__ W_in,
                                                    const float* __restrict__ Wa,
                                                    const float* __restrict__ bq,
                                                    const float* __restrict__ bk,
                                                    const float* __restrict__ bv,
                                                    const float* __restrict__ b_out,
                                                    const float* __restrict__ b_in,
                                                    const float* __restrict__ ba,
                                                    float* __restrict__ y) {
    int z = blockIdx.y;
    const float* W  = (z < 3) ? (W_in + (long)z * 1048576) : Wa;
    const float* b1 = (z == 0) ? bq : (z == 1) ? bk : (z == 2) ? bv : b_out;
    const float* b2 = (z < 3) ? (b_in + z * 1024) : ba;
    int row = blockIdx.x * 4 + (threadIdx.x >> 6);
    int lane = threadIdx.x & 63;
    const float* wr = W + (long)row * 1024;
    float s = 0.f;
    for (int k = lane; k < 1024; k += 64) s += wr[k] * b1[k];
#pragma unroll
    for (int o = 32; o >= 1; o >>= 1) s += __shfl_xor(s, o);
    if (lane == 0) y[z * 1024 + row] = b2[row] + s;
}

// ---------------- high-precision split-bf16 GEMM (register-prefetch pipeline) ----------------
enum { HP_SPLIT = 0, HP_F32 = 1, HP_SPLIT_HEADS = 2 };

template<int MODE>
__global__ __launch_bounds__(256)
void gemm_hp(const bf16* __restrict__ Ah, const bf16* __restrict__ Al, int lda, long sAz,
             const bf16* __restrict__ Bh, const bf16* __restrict__ Bl, int ldb, long sBz,
             void* __restrict__ Chv, bf16* __restrict__ Cl, int ldc, long sCz,
             const float* __restrict__ bias, long sbz, float alpha, int M, int N, int K) {
    __shared__ alignas(16) bf16 sAh[128 * 32];
    __shared__ alignas(16) bf16 sAl[128 * 32];
    __shared__ alignas(16) bf16 sBh[128 * 32];
    __shared__ alignas(16) bf16 sBl[128 * 32];
    const int bm = blockIdx.y, bn = blockIdx.x, z = blockIdx.z;
    const int tid  = threadIdx.x;
    const int lane = tid & 63, wave = tid >> 6;
    const int quad = lane >> 4, l16 = lane & 15;
    const int wr = wave >> 1, wc = wave & 1;
    const int sr = tid >> 2;
    const int sc = (tid & 3) * 8;

    int arow0 = min(bm * 128 + sr, M - 1);
    int arow1 = min(bm * 128 + sr + 64, M - 1);
    int brow0 = min(bn * 128 + sr, N - 1);
    int brow1 = min(bn * 128 + sr + 64, N - 1);

    const bf16* pAh0 = Ah + (long)z * sAz + (long)arow0 * lda + sc;
    const bf16* pAh1 = Ah + (long)z * sAz + (long)arow1 * lda + sc;
    const bf16* pAl0 = Al + (long)z * sAz + (long)arow0 * lda + sc;
    const bf16* pAl1 = Al + (long)z * sAz + (long)arow1 * lda + sc;
    const bf16* pBh0 = Bh + (long)z * sBz + (long)brow0 * ldb + sc;
    const bf16* pBh1 = Bh + (long)z * sBz + (long)brow1 * ldb + sc;
    const bf16* pBl0 = Bl + (long)z * sBz + (long)brow0 * ldb + sc;
    const bf16* pBl1 = Bl + (long)z * sBz + (long)brow1 * ldb + sc;
    const int wo = wave << 9;

    f32x4 acc[4][4];
#pragma unroll
    for (int i = 0; i < 4; i++)
#pragma unroll
        for (int j = 0; j < 4; j++) acc[i][j] = (f32x4){0.f, 0.f, 0.f, 0.f};

    // prologue: stage k=0
    ld16(sAh + wo,        pAh0);
    ld16(sAh + 2048 + wo, pAh1);
    ld16(sAl + wo,        pAl0);
    ld16(sAl + 2048 + wo, pAl1);
    ld16(sBh + wo,        pBh0);
    ld16(sBh + 2048 + wo, pBh1);
    ld16(sBl + wo,        pBl0);
    ld16(sBl + 2048 + wo, pBl1);
    __syncthreads();

    for (int k0 = 0; k0 < K; k0 += 32) {
        // read fragments of current tile into registers
        bf16x8 ah[4], al[4], bh[4], bl[4];
#pragma unroll
        for (int i = 0; i < 4; i++) {
            int ro = (wr * 64 + i * 16 + l16) * 32 + quad * 8;
            ah[i] = *(const bf16x8*)&sAh[ro];
            al[i] = *(const bf16x8*)&sAl[ro];
        }
#pragma unroll
        for (int j = 0; j < 4; j++) {
            int ro = (wc * 64 + j * 16 + l16) * 32 + quad * 8;
            bh[j] = *(const bf16x8*)&sBh[ro];
            bl[j] = *(const bf16x8*)&sBl[ro];
        }
        __syncthreads();   // all waves' reads complete -> safe to overwrite LDS
        int kn = k0 + 32;
        if (kn < K) {      // stage next tile; latency hides under the MFMAs below
            ld16(sAh + wo,        pAh0 + kn);
            ld16(sAh + 2048 + wo, pAh1 + kn);
            ld16(sAl + wo,        pAl0 + kn);
            ld16(sAl + 2048 + wo, pAl1 + kn);
            ld16(sBh + wo,        pBh0 + kn);
            ld16(sBh + 2048 + wo, pBh1 + kn);
            ld16(sBl + wo,        pBl0 + kn);
            ld16(sBl + 2048 + wo, pBl1 + kn);
        }
#pragma unroll
        for (int i = 0; i < 4; i++)
#pragma unroll
            for (int j = 0; j < 4; j++) {
                acc[i][j] = __builtin_amdgcn_mfma_f32_16x16x32_bf16(al[i], bh[j], acc[i][j], 0, 0, 0);
                acc[i][j] = __builtin_amdgcn_mfma_f32_16x16x32_bf16(ah[i], bl[j], acc[i][j], 0, 0, 0);
                acc[i][j] = __builtin_amdgcn_mfma_f32_16x16x32_bf16(ah[i], bh[j], acc[i][j], 0, 0, 0);
            }
        __syncthreads();   // implicit vmcnt(0): stage of kn complete
    }

#pragma unroll
    for (int i = 0; i < 4; i++) {
        int mbase = bm * 128 + wr * 64 + i * 16 + quad * 4;
#pragma unroll
        for (int j = 0; j < 4; j++) {
            int n = bn * 128 + wc * 64 + j * 16 + l16;
            if (n < N) {
                float bv = bias ? bias[(long)z * sbz + n] : 0.f;
#pragma unroll
                for (int r = 0; r < 4; r++) {
                    int m = mbase + r;
                    if (m < M) {
                        float v = alpha * acc[i][j][r] + bv;
                        if (MODE == HP_SPLIT) {
                            long cidx = (long)z * sCz + (long)m * ldc + n;
                            bf16 h = (bf16)v;
                            ((bf16*)Chv)[cidx] = h;
                            Cl[cidx] = (bf16)(v - (float)h);
                        } else if (MODE == HP_F32) {
                            long cidx = (long)z * sCz + (long)m * ldc + n;
                            ((float*)Chv)[cidx] = v;
                        } else {  // HP_SPLIT_HEADS: [slice=(b,h)][seq][64] (+ z offset)
                            int slice = ((m >> 10) << 4) + (n >> 6);
                            long idx = (long)z * sCz + (long)slice * 65536 + (long)(m & 1023) * 64 + (n & 63);
                            bf16 h = (bf16)v;
                            ((bf16*)Chv)[idx] = h;
                            Cl[idx] = (bf16)(v - (float)h);
                        }
                    }
                }
            }
        }
    }
}

// ---------------- PV GEMM: double-buffered pipeline ----------------
__global__ __launch_bounds__(256)
void gemm_pv(const bf16* __restrict__ Ph, const bf16* __restrict__ Pl,
             const bf16* __restrict__ Vh, const bf16* __restrict__ Vl,
             bf16* __restrict__ Oh, bf16* __restrict__ Ol) {
    __shared__ alignas(16) bf16 sAh[2][128 * 32];
    __shared__ alignas(16) bf16 sAl[2][128 * 32];
    __shared__ alignas(16) bf16 sBh[2][64 * 32];
    __shared__ alignas(16) bf16 sBl[2][64 * 32];
    const int bm = blockIdx.x, z = blockIdx.y;
    const int tid = threadIdx.x, lane = tid & 63, wave = tid >> 6;
    const int quad = lane >> 4, l16 = lane & 15;
    const int wr = wave & 1, wc = wave >> 1;
    const int sr = tid >> 2, sc = (tid & 3) * 8;

    const bf16* pA0h = Ph + (long)z * 1048576 + (long)(bm * 128 + sr) * 1024 + sc;
    const bf16* pA1h = pA0h + 64 * 1024;
    const bf16* pA0l = Pl + (long)z * 1048576 + (long)(bm * 128 + sr) * 1024 + sc;
    const bf16* pA1l = pA0l + 64 * 1024;
    const bf16* pB0h = Vh + (long)z * 65536 + (long)sr * 1024 + sc;
    const bf16* pB0l = Vl + (long)z * 65536 + (long)sr * 1024 + sc;
    const int wo = wave << 9;

    f32x4 acc[4][2];
#pragma unroll
    for (int i = 0; i < 4; i++)
#pragma unroll
        for (int j = 0; j < 2; j++) acc[i][j] = (f32x4){0.f, 0.f, 0.f, 0.f};

    // prologue: stage tile 0 into buf 0
    ld16(sAh[0] + wo,        pA0h);
    ld16(sAh[0] + 2048 + wo, pA1h);
    ld16(sAl[0] + wo,        pA0l);
    ld16(sAl[0] + 2048 + wo, pA1l);
    ld16(sBh[0] + wo, pB0h);
    ld16(sBl[0] + wo, pB0l);
    __syncthreads();

    int cur = 0;
    for (int k0 = 0; k0 < 1024; k0 += 32) {
        int kn = k0 + 32;
        if (kn < 1024) {   // stage next tile into other buffer
            ld16(sAh[cur ^ 1] + wo,        pA0h + kn);
            ld16(sAh[cur ^ 1] + 2048 + wo, pA1h + kn);
            ld16(sAl[cur ^ 1] + wo,        pA0l + kn);
            ld16(sAl[cur ^ 1] + 2048 + wo, pA1l + kn);
            ld16(sBh[cur ^ 1] + wo, pB0h + kn);
            ld16(sBl[cur ^ 1] + wo, pB0l + kn);
        }
        const bf16* cAh = sAh[cur]; const bf16* cAl = sAl[cur];
        const bf16* cBh = sBh[cur]; const bf16* cBl = sBl[cur];
        bf16x8 ah[4], al[4], bh[2], bl[2];
#pragma unroll
        for (int i = 0; i < 4; i++) {
            int ro = (wr * 64 + i * 16 + l16) * 32 + quad * 8;
            ah[i] = *(const bf16x8*)&cAh[ro];
            al[i] = *(const bf16x8*)&cAl[ro];
        }
#pragma unroll
        for (int j = 0; j < 2; j++) {
            int ro = (wc * 32 + j * 16 + l16) * 32 + quad * 8;
            bh[j] = *(const bf16x8*)&cBh[ro];
            bl[j] = *(const bf16x8*)&cBl[ro];
        }
#pragma unroll
        for (int i = 0; i < 4; i++)
#pragma unroll
            for (int j = 0; j < 2; j++) {
                acc[i][j] = __builtin_amdgcn_mfma_f32_16x16x32_bf16(al[i], bh[j], acc[i][j], 0, 0, 0);
                acc[i][j] = __builtin_amdgcn_mfma_f32_16x16x32_bf16(ah[i], bl[j], acc[i][j], 0, 0, 0);
                acc[i][j] = __builtin_amdgcn_mfma_f32_16x16x32_bf16(ah[i], bh[j], acc[i][j], 0, 0, 0);
            }
        __syncthreads();   // stage done (vmcnt0) + all reads of cur done
        cur ^= 1;
    }

#pragma unroll
    for (int i = 0; i < 4; i++) {
        int mbase = bm * 128 + wr * 64 + i * 16 + quad * 4;
#pragma unroll
        for (int j = 0; j < 2; j++) {
            int n = wc * 32 + j * 16 + l16;
#pragma unroll
            for (int r = 0; r < 4; r++) {
                int m = mbase + r;
                long idx = (long)z * 65536 + (long)m * 64 + n;
                float v = acc[i][j][r];
                bf16 h = (bf16)v;
                Oh[idx] = h;
                Ol[idx] = (bf16)(v - (float)h);
            }
        }
    }
}

// ---------------- MoE GEMM1 (compacted tile grid, dbuf pipeline, GELU epilogue) ----------------
__global__ __launch_bounds__(256)
void gemm_moe1(const bf16* __restrict__ Ae, const bf16* __restrict__ ew1t,
               const float* __restrict__ eb1, bf16* __restrict__ Hp,
               const int* __restrict__ counts, const int* __restrict__ bases,
               const int* __restrict__ tiles, const int* __restrict__ ntile) {
    const int wg = xcd_swz(blockIdx.x, gridDim.x);
    const int tile = wg >> 5;
    const int bn = wg & 31;
    if (tile >= ntile[0]) return;
    const int te = tiles[tile];
    const int e = te >> 16, bm = te & 0xffff;
    const int M = counts[e];
    const bf16* A = Ae + (long)bases[e] * 1024;
    const bf16* B = ew1t + (long)e * 4194304;
    bf16* C = Hp + (long)bases[e] * 4096;
    const float* bias = eb1 + e * 4096;

    __shared__ alignas(16) bf16 sA[2][128 * 32];
    __shared__ alignas(16) bf16 sB[2][128 * 32];
    const int tid  = threadIdx.x;
    const int lane = tid & 63, wave = tid >> 6;
    const int quad = lane >> 4, l16 = lane & 15;
    const int wr = wave >> 1, wc = wave & 1;
    const int sr = tid >> 2;
    const int sc = (tid & 3) * 8;

    int arow0 = min(bm * 128 + sr, M - 1);
    int arow1 = min(bm * 128 + sr + 64, M - 1);
    int brow0 = bn * 128 + sr;
    const bf16* pA0 = A + (long)arow0 * 1024 + sc;
    const bf16* pA1 = A + (long)arow1 * 1024 + sc;
    const bf16* pB0 = B + (long)brow0 * 1024 + sc;
    const bf16* pB1 = B + (long)(brow0 + 64) * 1024 + sc;
    const int wo = wave << 9;

    f32x4 acc[4][4];
#pragma unroll
    for (int i = 0; i < 4; i++)
#pragma unroll
        for (int j = 0; j < 4; j++) acc[i][j] = (f32x4){0.f, 0.f, 0.f, 0.f};

    // prologue
    ld16(sA[0] + wo,        pA0);
    ld16(sA[0] + 2048 + wo, pA1);
    ld16(sB[0] + wo,        pB0);
    ld16(sB[0] + 2048 + wo, pB1);
    __syncthreads();

    int cur = 0;
    for (int k0 = 0; k0 < 1024; k0 += 32) {
        int kn = k0 + 32;
        if (kn < 1024) {
            ld16(sA[cur ^ 1] + wo,        pA0 + kn);
            ld16(sA[cur ^ 1] + 2048 + wo, pA1 + kn);
            ld16(sB[cur ^ 1] + wo,        pB0 + kn);
            ld16(sB[cur ^ 1] + 2048 + wo, pB1 + kn);
        }
        const bf16* cA = sA[cur]; const bf16* cB = sB[cur];
        bf16x8 af[4], bfr[4];
#pragma unroll
        for (int i = 0; i < 4; i++)
            af[i] = *(const bf16x8*)&cA[(wr * 64 + i * 16 + l16) * 32 + quad * 8];
#pragma unroll
        for (int j = 0; j < 4; j++)
            bfr[j] = *(const bf16x8*)&cB[(wc * 64 + j * 16 + l16) * 32 + quad * 8];
#pragma unroll
        for (int i = 0; i < 4; i++)
#pragma unroll
            for (int j = 0; j < 4; j++)
                acc[i][j] = __builtin_amdgcn_mfma_f32_16x16x32_bf16(af[i], bfr[j], acc[i][j], 0, 0, 0);
        __syncthreads();
        cur ^= 1;
    }

#pragma unroll
    for (int i = 0; i < 4; i++) {
        int mbase = bm * 128 + wr * 64 + i * 16 + quad * 4;
#pragma unroll
        for (int j = 0; j < 4; j++) {
            int n = bn * 128 + wc * 64 + j * 16 + l16;
            float bv = bias[n];
#pragma unroll
            for (int r = 0; r < 4; r++) {
                int m = mbase + r;
                if (m < M) {
                    float v = acc[i][j][r] + bv;
                    float g = 0.5f * v * (1.f + erff(v * 0.70710678118654752f));
                    C[(long)m * 4096 + n] = (bf16)g;
                }
            }
        }
    }
}

// ---------------- MoE GEMM2 (compacted tile grid, dbuf pipeline, fp32 out) ----------------
__global__ __launch_bounds__(256)
void gemm_moe2(const bf16* __restrict__ Hp, const bf16* __restrict__ ew2t,
               float* __restrict__ Y,
               const int* __restrict__ counts, const int* __restrict__ bases,
               const int* __restrict__ tiles, const int* __restrict__ ntile) {
    const int wg = xcd_swz(blockIdx.x, gridDim.x);
    const int tile = wg >> 3;
    const int bn = wg & 7;
    if (tile >= ntile[0]) return;
    const int te = tiles[tile];
    const int e = te >> 16, bm = te & 0xffff;
    const int M = counts[e];
    const bf16* A = Hp + (long)bases[e] * 4096;
    const bf16* B = ew2t + (long)e * 4194304;
    float* C = Y + (long)bases[e] * 1024;

    __shared__ alignas(16) bf16 sA[2][128 * 32];
    __shared__ alignas(16) bf16 sB[2][128 * 32];
    const int tid  = threadIdx.x;
    const int lane = tid & 63, wave = tid >> 6;
    const int quad = lane >> 4, l16 = lane & 15;
    const int wr = wave >> 1, wc = wave & 1;
    const int sr = tid >> 2;
    const int sc = (tid & 3) * 8;

    int arow0 = min(bm * 128 + sr, M - 1);
    int arow1 = min(bm * 128 + sr + 64, M - 1);
    int brow0 = bn * 128 + sr;
    const bf16* pA0 = A + (long)arow0 * 4096 + sc;
    const bf16* pA1 = A + (long)arow1 * 4096 + sc;
    const bf16* pB0 = B + (long)brow0 * 4096 + sc;
    const bf16* pB1 = B + (long)(brow0 + 64) * 4096 + sc;
    const int wo = wave << 9;

    f32x4 acc[4][4];
#pragma unroll
    for (int i = 0; i < 4; i++)
#pragma unroll
        for (int j = 0; j < 4; j++) acc[i][j] = (f32x4){0.f, 0.f, 0.f, 0.f};

    // prologue
    ld16(sA[0] + wo,        pA0);
    ld16(sA[0] + 2048 + wo, pA1);
    ld16(sB[0] + wo,        pB0);
    ld16(sB[0] + 2048 + wo, pB1);
    __syncthreads();

    int cur = 0;
    for (int k0 = 0; k0 < 4096; k0 += 32) {
        int kn = k0 + 32;
        if (kn < 4096) {
            ld16(sA[cur ^ 1] + wo,        pA0 + kn);
            ld16(sA[cur ^ 1] + 2048 + wo, pA1 + kn);
            ld16(sB[cur ^ 1] + wo,        pB0 + kn);
            ld16(sB[cur ^ 1] + 2048 + wo, pB1 + kn);
        }
        const bf16* cA = sA[cur]; const bf16* cB = sB[cur];
        bf16x8 af[4], bfr[4];
#pragma unroll
        for (int i = 0; i < 4; i++)
            af[i] = *(const bf16x8*)&cA[(wr * 64 + i * 16 + l16) * 32 + quad * 8];
#pragma unroll
        for (int j = 0; j < 4; j++)
            bfr[j] = *(const bf16x8*)&cB[(wc * 64 + j * 16 + l16) * 32 + quad * 8];
#pragma unroll
        for (int i = 0; i < 4; i++)
#pragma unroll
            for (int j = 0; j < 4; j++)
                acc[i][j] = __builtin_amdgcn_mfma_f32_16x16x32_bf16(af[i], bfr[j], acc[i][j], 0, 0, 0);
        __syncthreads();
        cur ^= 1;
    }

#pragma unroll
    for (int i = 0; i < 4; i++) {
        int mbase = bm * 128 + wr * 64 + i * 16 + quad * 4;
#pragma unroll
        for (int j = 0; j < 4; j++) {
            int n = bn * 128 + wc * 64 + j * 16 + l16;
#pragma unroll
            for (int r = 0; r < 4; r++) {
                int m = mbase + r;
                if (m < M) C[(long)m * 1024 + n] = acc[i][j][r];
            }
        }
    }
}

// ---------------- per-slice V transpose ----------------
__global__ __launch_bounds__(256) void k_vsplit(const bf16* __restrict__ VH_h,
                                                const bf16* __restrict__ VH_l,
                                                bf16* __restrict__ VT_h,
                                                bf16* __restrict__ VT_l) {
    __shared__ bf16 th[64][65];
    __shared__ bf16 tl[64][65];
    int s = blockIdx.y, q0 = blockIdx.x * 64;
    int b = s >> 4, h = s & 15;
    long ibase = ((long)(b * 1024 + q0)) * 1024 + h * 64;
    for (int i = threadIdx.x; i < 4096; i += 256) {
        int q = i >> 6, d = i & 63;
        th[q][d] = VH_h[ibase + (long)q * 1024 + d];
        tl[q][d] = VH_l[ibase + (long)q * 1024 + d];
    }
    __syncthreads();
    long obase = (long)s * 65536 + q0;
    for (int i = threadIdx.x; i < 4096; i += 256) {
        int d = i >> 6, q = i & 63;
        VT_h[obase + (long)d * 1024 + q] = th[q][d];
        VT_l[obase + (long)d * 1024 + q] = tl[q][d];
    }
}

// ---------------- O reassembly ----------------
__global__ __launch_bounds__(256) void k_ocopy(const bf16* __restrict__ Op_h,
                                               const bf16* __restrict__ Op_l,
                                               bf16* __restrict__ O_h,
                                               bf16* __restrict__ O_l) {
    int t = blockIdx.x * 4 + (threadIdx.x >> 6);
    int lane = threadIdx.x & 63;
    int b = t >> 10, q = t & 1023;
    int h = lane >> 2, dd = (lane & 3) * 16;
    long src = ((long)(b * 16 + h)) * 65536 + (long)q * 64 + dd;
    long dst = (long)t * 1024 + h * 64 + dd;
    *(bf16x8*)(O_h + dst)     = *(const bf16x8*)(Op_h + src);
    *(bf16x8*)(O_h + dst + 8) = *(const bf16x8*)(Op_h + src + 8);
    *(bf16x8*)(O_l + dst)     = *(const bf16x8*)(Op_l + src);
    *(bf16x8*)(O_l + dst + 8) = *(const bf16x8*)(Op_l + src + 8);
}

// ---------------- gather expert rows (packed) ----------------
__global__ __launch_bounds__(256) void k_gather(const bf16* __restrict__ Xb,
                                                const int* __restrict__ tok,
                                                const int* __restrict__ counts,
                                                const int* __restrict__ bases,
                                                bf16* __restrict__ Ae) {
    int e = blockIdx.y;
    int cnt = counts[e];
    long base = bases[e];
    for (int i = blockIdx.x; i < cnt; i += gridDim.x) {
        int t = tok[e * 4096 + i];
        const bf16x4* src = (const bf16x4*)(Xb + (long)t * 1024);
        bf16x4* dst = (bf16x4*)(Ae + (base + i) * 1024);
        dst[threadIdx.x] = src[threadIdx.x];
    }
}

// ---------------- in-place softmax on split rows ----------------
__global__ __launch_bounds__(256) void k_softmax_ip(bf16* __restrict__ Sh,
                                                    bf16* __restrict__ Sl) {
    int row = blockIdx.x * 4 + (threadIdx.x >> 6);
    int lane = threadIdx.x & 63;
    long o = (long)row * 1024 + lane * 16;
    bf16x8 h0 = *(const bf16x8*)(Sh + o), h1 = *(const bf16x8*)(Sh + o + 8);
    bf16x8 l0 = *(const bf16x8*)(Sl + o), l1 = *(const bf16x8*)(Sl + o + 8);
    float v[16];
#pragma unroll
    for (int i = 0; i < 8; i++) {
        v[i] = (float)h0[i] + (float)l0[i];
        v[8 + i] = (float)h1[i] + (float)l1[i];
    }
    float mx = v[0];
#pragma unroll
    for (int i = 1; i < 16; i++) mx = fmaxf(mx, v[i]);
#pragma unroll
    for (int of = 32; of >= 1; of >>= 1) mx = fmaxf(mx, __shfl_xor(mx, of));
    float s = 0.f;
#pragma unroll
    for (int i = 0; i < 16; i++) { v[i] = expf(v[i] - mx); s += v[i]; }
#pragma unroll
    for (int of = 32; of >= 1; of >>= 1) s += __shfl_xor(s, of);
    float inv = 1.f / s;
#pragma unroll
    for (int i = 0; i < 8; i++) {
        float a = v[i] * inv;
        h0[i] = (bf16)a; l0[i] = (bf16)(a - (float)h0[i]);
        float b = v[8 + i] * inv;
        h1[i] = (bf16)b; l1[i] = (bf16)(b - (float)h1[i]);
    }
    *(bf16x8*)(Sh + o) = h0;  *(bf16x8*)(Sh + o + 8) = h1;
    *(bf16x8*)(Sl + o) = l0;  *(bf16x8*)(Sl + o + 8) = l1;
}

// ---------------- layernorm ----------------
__global__ __launch_bounds__(256) void k_ln(const float* __restrict__ xin,
                                            const float* __restrict__ resid,
                                            const float* __restrict__ g,
                                            const float* __restrict__ bb,
                                            float* __restrict__ outf,
                                            bf16* __restrict__ outb) {
    int row = blockIdx.x * 4 + (threadIdx.x >> 6);
    int lane = threadIdx.x & 63;
    long base = (long)row * 1024 + lane * 16;
    float v[16];
#pragma unroll
    for (int i = 0; i < 16; i += 4) {
        f32x4 a = *(const f32x4*)(xin + base + i);
        if (resid) { f32x4 r4 = *(const f32x4*)(resid + base + i); a += r4; }
        v[i] = a[0]; v[i + 1] = a[1]; v[i + 2] = a[2]; v[i + 3] = a[3];
    }
    float s = 0.f;
#pragma unroll
    for (int i = 0; i < 16; i++) s += v[i];
#pragma unroll
    for (int o = 32; o >= 1; o >>= 1) s += __shfl_xor(s, o);
    float mean = s * (1.f / 1024.f);
    float vs = 0.f;
#pragma unroll
    for (int i = 0; i < 16; i++) { float d = v[i] - mean; vs += d * d; }
#pragma unroll
    for (int o = 32; o >= 1; o >>= 1) vs += __shfl_xor(vs, o);
    float inv = 1.f / sqrtf(vs * (1.f / 1024.f) + 1e-5f);
    const float* gp = g + lane * 16;
    const float* bp = bb + lane * 16;
#pragma unroll
    for (int i = 0; i < 16; i++) {
        float o = (v[i] - mean) * inv * gp[i] + bp[i];
        if (outf) outf[base + i] = o;
        if (outb) outb[base + i] = (bf16)o;
    }
}

// ---------------- fused MoE combine + residual + LN2 ----------------
__global__ __launch_bounds__(256) void k_moe_ln(const float* __restrict__ Y,
                                                const int* __restrict__ pos,
                                                const float* __restrict__ combine,
                                                const float* __restrict__ eb2,
                                                const float* __restrict__ resid,
                                                const float* __restrict__ g,
                                                const float* __restrict__ bb,
                                                float* __restrict__ outf) {
    int row = blockIdx.x * 4 + (threadIdx.x >> 6);
    int lane = threadIdx.x & 63;
    long base = (long)row * 1024 + lane * 16;
    float v[16];
#pragma unroll
    for (int i = 0; i < 16; i += 4) {
        f32x4 a = *(const f32x4*)(resid + base + i);
        v[i] = a[0]; v[i + 1] = a[1]; v[i + 2] = a[2]; v[i + 3] = a[3];
    }
    for (int e = 0; e < 8; e++) {
        int p = pos[row * 8 + e];
        if (p >= 0) {
            float c = combine[row * 8 + e];
            const float* yr = Y + (long)p * 1024 + lane * 16;
            const float* br = eb2 + e * 1024 + lane * 16;
#pragma unroll
            for (int i = 0; i < 16; i += 4) {
                f32x4 y4 = *(const f32x4*)(yr + i);
                f32x4 b4 = *(const f32x4*)(br + i);
                v[i]     += c * (y4[0] + b4[0]);
                v[i + 1] += c * (y4[1] + b4[1]);
                v[i + 2] += c * (y4[2] + b4[2]);
                v[i + 3] += c * (y4[3] + b4[3]);
            }
        }
    }
    float s = 0.f;
#pragma unroll
    for (int i = 0; i < 16; i++) s += v[i];
#pragma unroll
    for (int o = 32; o >= 1; o >>= 1) s += __shfl_xor(s, o);
    float mean = s * (1.f / 1024.f);
    float vs = 0.f;
#pragma unroll
    for (int i = 0; i < 16; i++) { float d = v[i] - mean; vs += d * d; }
#pragma unroll
    for (int o = 32; o >= 1; o >>= 1) vs += __shfl_xor(vs, o);
    float inv = 1.f / sqrtf(vs * (1.f / 1024.f) + 1e-5f);
    const float* gp = g + lane * 16;
    const float* bp = bb + lane * 16;
#pragma unroll
    for (int i = 0; i < 16; i++)
        outf[base + i] = (v[i] - mean) * inv * gp[i] + bp[i];
}

// ---------------- gating (no routing atomics) ----------------
__global__ __launch_bounds__(256) void k_gate(const float* __restrict__ X,
                                              const float* __restrict__ Wg,
                                              float* __restrict__ combine,
                                              float* __restrict__ partials) {
    __shared__ float sm[16];
    if (threadIdx.x < 16) sm[threadIdx.x] = 0.f;
    __syncthreads();
    int t = blockIdx.x * 4 + (threadIdx.x >> 6);
    int lane = threadIdx.x & 63;
    const float* x = X + (long)t * 1024;
    float acc[8] = {0.f, 0.f, 0.f, 0.f, 0.f, 0.f, 0.f, 0.f};
    for (int i = lane; i < 1024; i += 64) {
        float xv = x[i];
        const float* w = Wg + i * 8;
#pragma unroll
        for (int e = 0; e < 8; e++) acc[e] += xv * w[e];
    }
#pragma unroll
    for (int e = 0; e < 8; e++)
#pragma unroll
        for (int o = 32; o >= 1; o >>= 1) acc[e] += __shfl_xor(acc[e], o);
    if (lane == 0) {
        float mx = acc[0];
#pragma unroll
        for (int e = 1; e < 8; e++) mx = fmaxf(mx, acc[e]);
        float p[8], s = 0.f;
#pragma unroll
        for (int e = 0; e < 8; e++) { p[e] = expf(acc[e] - mx); s += p[e]; }
        float invs = 1.f / s;
#pragma unroll
        for (int e = 0; e < 8; e++) p[e] *= invs;
        float b1 = -1.f, b2 = -1.f, b3 = -1.f; int i1 = 0, i2 = 0, i3 = 0;
#pragma unroll
        for (int e = 0; e < 8; e++) {
            float pe = p[e];
            if (pe > b1)      { b3 = b2; i3 = i2; b2 = b1; i2 = i1; b1 = pe; i1 = e; }
            else if (pe > b2) { b3 = b2; i3 = i2; b2 = pe; i2 = e; }
            else if (pe > b3) { b3 = pe; i3 = e; }
        }
        float c[8] = {0.f, 0.f, 0.f, 0.f, 0.f, 0.f, 0.f, 0.f};
        c[i1] = b1;
        if (b2 >= THRESH_C) c[i2] = b2;
        if (b3 >= THRESH_C) c[i3] = b3;
        float* co = combine + (long)t * 8;
#pragma unroll
        for (int e = 0; e < 8; e++) co[e] = c[e];
#pragma unroll
        for (int e = 0; e < 8; e++) {
            atomicAdd(&sm[e], p[e]);
            if (c[e] > 0.f) atomicAdd(&sm[8 + e], 1.f);
        }
    }
    __syncthreads();
    if (threadIdx.x < 16) partials[(long)blockIdx.x * 16 + threadIdx.x] = sm[threadIdx.x];
}

// ---------------- deterministic routing ----------------
__global__ __launch_bounds__(256) void k_route(const float* __restrict__ combine,
                                               int* __restrict__ counts,
                                               int* __restrict__ bases,
                                               int* __restrict__ tok,
                                               int* __restrict__ pos,
                                               int* __restrict__ tiles,
                                               int* __restrict__ ntile) {
    __shared__ int scan[256];
    int tid = threadIdx.x;
    int mybase = 0;
    int nt = 0;
    for (int e = 0; e < 8; e++) {
        int pred[16]; int cnt = 0;
#pragma unroll
        for (int j = 0; j < 16; j++) {
            int t = tid * 16 + j;
            pred[j] = combine[t * 8 + e] > 0.f ? 1 : 0;
            cnt += pred[j];
        }
        scan[tid] = cnt;
        __syncthreads();
        for (int off = 1; off < 256; off <<= 1) {
            int v = (tid >= off) ? scan[tid - off] : 0;
            __syncthreads();
            scan[tid] += v;
            __syncthreads();
        }
        int start = scan[tid] - cnt;
        int total = scan[255];
        int o = e * 4096 + start;
        int gp = mybase + start;
#pragma unroll
        for (int j = 0; j < 16; j++) {
            int t = tid * 16 + j;
            if (pred[j]) { tok[o++] = t; pos[t * 8 + e] = gp++; }
            else pos[t * 8 + e] = -1;
        }
        if (tid == 0) {
            counts[e] = total; bases[e] = mybase;
            int nte = (total + 127) >> 7;
            for (int b = 0; b < nte; b++) tiles[nt++] = (e << 16) | b;
        }
        mybase += total;
        __syncthreads();
    }
    if (tid == 0) ntile[0] = nt;
}

// ---------------- aux reduce ----------------
__global__ __launch_bounds__(256) void k_aux(const float* __restrict__ partials, int nblocks,
                                             float* __restrict__ auxout) {
    __shared__ float red[256];
    int tid = threadIdx.x;
    int e = tid & 15, grp = tid >> 4;
    float s = 0.f;
    for (int b = grp; b < nblocks; b += 16) s += partials[(long)b * 16 + e];
    red[tid] = s;
    __syncthreads();
    if (grp == 0) {
        float tot = 0.f;
        for (int g2 = 0; g2 < 16; g2++) tot += red[g2 * 16 + e];
        red[tid] = tot;
    }
    __syncthreads();
    if (tid == 0) {
        float s2 = 0.f;
        for (int e2 = 0; e2 < 8; e2++)
            s2 += (red[8 + e2] * (1.f / 4096.f)) * (red[e2] * (1.f / 4096.f));
        auxout[0] = COEF_C * 8.f * s2;
    }
}

// ---------------- host ----------------
extern "C" void kernel_launch(void* const* d_in, const int* in_sizes, int n_in,
                              void* d_out, int out_size, void* d_ws, size_t ws_size,
                              hipStream_t stream) {
    const float* query     = (const float*)d_in[0];
    const float* key_value = (const float*)d_in[1];
    const float* Wq   = (const float*)d_in[2];
    const float* bq   = (const float*)d_in[3];
    const float* Wk   = (const float*)d_in[4];
    const float* bk   = (const float*)d_in[5];
    const float* Wv   = (const float*)d_in[6];
    const float* bv   = (const float*)d_in[7];
    const float* W_in = (const float*)d_in[8];
    const float* b_in = (const float*)d_in[9];
    const float* W_out = (const float*)d_in[10];
    const float* b_out = (const float*)d_in[11];
    const float* Wa   = (const float*)d_in[12];
    const float* ba   = (const float*)d_in[13];
    const float* ln1_g = (const float*)d_in[14];
    const float* ln1_b = (const float*)d_in[15];
    const float* Wg   = (const float*)d_in[16];
    const float* ew1  = (const float*)d_in[17];
    const float* eb1  = (const float*)d_in[18];
    const float* ew2  = (const float*)d_in[19];
    const float* eb2  = (const float*)d_in[20];
    const float* ln2_g = (const float*)d_in[21];
    const float* ln2_b = (const float*)d_in[22];

    const size_t MBY = 1ull << 20;
    const long MB1 = 1024L * 1024L;
    char* ws = (char*)d_ws;

    bf16* Sh   = (bf16*)(ws + 0 * MBY);
    bf16* Sl   = (bf16*)(ws + 64 * MBY);
    bf16* ew1t = (bf16*)(ws + 0 * MBY);
    bf16* ew2t = (bf16*)(ws + 64 * MBY);
    bf16* WAll_h = (bf16*)(ws + 128 * MBY);
    bf16* WAll_l = (bf16*)(ws + 136 * MBY);
    bf16* WT_h   = (bf16*)(ws + 144 * MBY);
    bf16* WT_l   = (bf16*)(ws + 152 * MBY);
    bf16* Xq_h  = (bf16*)(ws + 160 * MBY), *Xq_l  = (bf16*)(ws + 168 * MBY);
    bf16* Xkv_h = (bf16*)(ws + 176 * MBY), *Xkv_l = (bf16*)(ws + 184 * MBY);
    bf16* O_h  = (bf16*)(ws + 160 * MBY), *O_l  = (bf16*)(ws + 168 * MBY);
    bf16* QHp_h = (bf16*)(ws + 192 * MBY), *QHp_l = (bf16*)(ws + 200 * MBY);
    bf16* KHp_h = (bf16*)(ws + 208 * MBY), *KHp_l = (bf16*)(ws + 216 * MBY);
    bf16* VH_h  = (bf16*)(ws + 224 * MBY), *VH_l  = (bf16*)(ws + 232 * MBY);
    bf16* VTp_h = (bf16*)(ws + 240 * MBY), *VTp_l = (bf16*)(ws + 248 * MBY);
    bf16* Op_h  = (bf16*)(ws + 256 * MBY), *Op_l  = (bf16*)(ws + 264 * MBY);
    float* Xf   = (float*)(ws + 256 * MBY);
    float* Af   = (float*)(ws + 272 * MBY);
    bf16* Ae      = (bf16*)(ws + 128 * MBY);
    bf16* Hp      = (bf16*)(ws + 152 * MBY);
    float* Yp     = (float*)(ws + 272 * MBY);
    bf16* Xb   = (bf16*)(ws + 320 * MBY);
    bf16* Weff_h = (bf16*)(ws + 328 * MBY);
    bf16* Weff_l = (bf16*)(ws + 336 * MBY);
    float* combine  = (float*)(ws + 344 * MBY);
    float* partials = (float*)(ws + 344 * MBY + 128 * 1024);
    float* beff     = (float*)(ws + 344 * MBY + 192 * 1024);
    int*   counts   = (int*)  (ws + 344 * MBY + 212 * 1024);
    int*   bases    = (int*)  (ws + 344 * MBY + 213 * 1024);
    int*   tok      = (int*)  (ws + 344 * MBY + 214 * 1024);
    int*   pos      = (int*)  (ws + 344 * MBY + 342 * 1024);
    int*   tiles    = (int*)  (ws + 344 * MBY + 472 * 1024);
    int*   ntile    = tiles + 128;

    dim3 blk(256);

    // ---- prep ----
    k_f32_to_split<<<4096, blk, 0, stream>>>(query, Xq_h, Xq_l, 4L * MB1);
    k_f32_to_split<<<4096, blk, 0, stream>>>(key_value, Xkv_h, Xkv_l, 4L * MB1);
    k_f32_to_split<<<3072, blk, 0, stream>>>(W_in, WAll_h, WAll_l, 3L * MB1);
    k_f32_to_split<<<1024, blk, 0, stream>>>(Wa, WAll_h + 3 * MB1, WAll_l + 3 * MB1, MB1);
    k_transpose4_split<<<dim3(16, 16, 4), blk, 0, stream>>>(Wq, Wk, Wv, W_out, WT_h, WT_l);
    k_bias_fold4<<<dim3(256, 4), blk, 0, stream>>>(W_in, Wa, bq, bk, bv, b_out, b_in, ba, beff);

    // ---- weight folds ----
    gemm_hp<HP_SPLIT><<<dim3(8, 8, 4), blk, 0, stream>>>(
        WAll_h, WAll_l, 1024, MB1, WT_h, WT_l, 1024, MB1,
        Weff_h, Weff_l, 1024, MB1, nullptr, 0, 1.f, 1024, 1024, 1024);

    // ---- projections: Q+K merged (z=2), V separate ----
    gemm_hp<HP_SPLIT_HEADS><<<dim3(8, 32, 2), blk, 0, stream>>>(
        Xq_h, Xq_l, 1024, 8 * MB1, Weff_h, Weff_l, 1024, MB1,
        QHp_h, QHp_l, 0, 8 * MB1, beff, 1024, 1.f, 4096, 1024, 1024);
    gemm_hp<HP_SPLIT><<<dim3(8, 32, 1), blk, 0, stream>>>(
        Xkv_h, Xkv_l, 1024, 0, Weff_h + 2 * MB1, Weff_l + 2 * MB1, 1024, 0,
        VH_h, VH_l, 1024, 0, beff + 2048, 0, 1.f, 4096, 1024, 1024);
    k_vsplit<<<dim3(16, 64), blk, 0, stream>>>(VH_h, VH_l, VTp_h, VTp_l);

    // ---- attention: 2 halves of 32 (b,h) slices ----
    for (int half = 0; half < 2; half++) {
        long so = (long)half * 32 * 65536;
        gemm_hp<HP_SPLIT><<<dim3(8, 8, 32), blk, 0, stream>>>(
            QHp_h + so, QHp_l + so, 64, 65536,
            KHp_h + so, KHp_l + so, 64, 65536,
            Sh, Sl, 1024, MB1, nullptr, 0, 0.125f, 1024, 1024, 64);
        k_softmax_ip<<<8192, blk, 0, stream>>>(Sh, Sl);
        gemm_pv<<<dim3(8, 32), blk, 0, stream>>>(Sh, Sl, VTp_h + so, VTp_l + so,
                                                 Op_h + so, Op_l + so);
    }
    k_ocopy<<<1024, blk, 0, stream>>>(Op_h, Op_l, O_h, O_l);

    // ---- out-proj+adapter (folded) + LN1 + gate + route ----
    gemm_hp<HP_F32><<<dim3(8, 32, 1), blk, 0, stream>>>(
        O_h, O_l, 1024, 0, Weff_h + 3 * MB1, Weff_l + 3 * MB1, 1024, 0,
        Af, nullptr, 1024, 0, beff + 3072, 0, 1.f, 4096, 1024, 1024);
    k_ln<<<1024, blk, 0, stream>>>(Af, query, ln1_g, ln1_b, Xf, Xb);
    k_gate<<<1024, blk, 0, stream>>>(Xf, Wg, combine, partials);
    k_route<<<1, blk, 0, stream>>>(combine, counts, bases, tok, pos, tiles, ntile);
    k_gather<<<dim3(512, 8), blk, 0, stream>>>(Xb, tok, counts, bases, Ae);

    // ---- expert weight transposes ----
    k_transpose_ew<<<dim3(64, 16, 8), blk, 0, stream>>>(ew1, ew1t, 1024, 4096);
    k_transpose_ew<<<dim3(16, 64, 8), blk, 0, stream>>>(ew2, ew2t, 4096, 1024);

    // ---- batched routed MoE ----
    gemm_moe1<<<dim3(104 * 32), blk, 0, stream>>>(Ae, ew1t, eb1, Hp, counts, bases, tiles, ntile);
    gemm_moe2<<<dim3(104 * 8), blk, 0, stream>>>(Hp, ew2t, Yp, counts, bases, tiles, ntile);

    // ---- fused MoE combine + residual + LN2, then aux ----
    k_moe_ln<<<1024, blk, 0, stream>>>(Yp, pos, combine, eb2, Xf, ln2_g, ln2_b, (float*)d_out);
    k_aux<<<1, blk, 0, stream>>>(partials, 1024, (float*)d_out + (out_size - 1));
}

// Round 6
// 1457.968 us; speedup vs baseline: 1.1029x; 1.0644x over previous
//
#include <hip/hip_runtime.h>
#include <math.h>

#define THRESH_C 0.05f
#define COEF_C   0.01f

typedef __bf16 bf16;
typedef __bf16 bf16x8 __attribute__((ext_vector_type(8)));
typedef __bf16 bf16x4 __attribute__((ext_vector_type(4)));
typedef float  f32x4  __attribute__((ext_vector_type(4)));

// async global->LDS, 16B per lane, dest = wave-uniform base + lane*16
__device__ __forceinline__ void ld16(void* lds_base, const void* g) {
    __builtin_amdgcn_global_load_lds(
        (const __attribute__((address_space(1))) void*)g,
        (__attribute__((address_space(3))) void*)lds_base,
        16, 0, 0);
}

// bijective XCD swizzle (m204)
__device__ __forceinline__ int xcd_swz(int orig, int nwg) {
    int q = nwg >> 3, r = nwg & 7;
    int xcd = orig & 7, idx = orig >> 3;
    return (xcd < r ? xcd * (q + 1) : r * (q + 1) + (xcd - r) * q) + idx;
}

// ---------------- f32 -> split (hi+lo bf16) ----------------
__global__ __launch_bounds__(256) void k_f32_to_split(const float* __restrict__ in,
                                                      bf16* __restrict__ hi,
                                                      bf16* __restrict__ lo, long n) {
    long i = ((long)blockIdx.x * 256 + threadIdx.x) * 4;
    if (i >= n) return;
    float4 v = *(const float4*)(in + i);
    bf16x4 h, l;
    h[0] = (bf16)v.x; l[0] = (bf16)(v.x - (float)h[0]);
    h[1] = (bf16)v.y; l[1] = (bf16)(v.y - (float)h[1]);
    h[2] = (bf16)v.z; l[2] = (bf16)(v.z - (float)h[2]);
    h[3] = (bf16)v.w; l[3] = (bf16)(v.w - (float)h[3]);
    *(bf16x4*)(hi + i) = h;
    *(bf16x4*)(lo + i) = l;
}

// ---------------- merged 4-way f32 transpose -> split ----------------
__global__ __launch_bounds__(256) void k_transpose4_split(const float* __restrict__ w0,
                                                          const float* __restrict__ w1,
                                                          const float* __restrict__ w2,
                                                          const float* __restrict__ w3,
                                                          bf16* __restrict__ oh,
                                                          bf16* __restrict__ ol) {
    __shared__ float t[64][65];
    int z = blockIdx.z;
    const float* in = (z == 0) ? w0 : (z == 1) ? w1 : (z == 2) ? w2 : w3;
    bf16* ohz = oh + (long)z * 1048576;
    bf16* olz = ol + (long)z * 1048576;
    int r0 = blockIdx.y * 64, c0 = blockIdx.x * 64;
    for (int i = threadIdx.x; i < 4096; i += 256) {
        int r = i >> 6, c = i & 63;
        t[r][c] = in[(long)(r0 + r) * 1024 + (c0 + c)];
    }
    __syncthreads();
    for (int i = threadIdx.x; i < 4096; i += 256) {
        int c = i >> 6, r = i & 63;
        float v = t[r][c];
        bf16 h = (bf16)v;
        long o = (long)(c0 + c) * 1024 + (r0 + r);
        ohz[o] = h;
        olz[o] = (bf16)(v - (float)h);
    }
}

// ---------------- expert weight transpose to bf16 ----------------
__global__ __launch_bounds__(256) void k_transpose_ew(const float* __restrict__ in,
                                                      bf16* __restrict__ out,
                                                      int R, int C) {
    __shared__ bf16 t[64][65];
    const float* ib = in + (long)blockIdx.z * R * C;
    bf16* ob = out + (long)blockIdx.z * R * C;
    int r0 = blockIdx.y * 64, c0 = blockIdx.x * 64;
    for (int i = threadIdx.x; i < 4096; i += 256) {
        int r = i >> 6, c = i & 63;
        t[r][c] = (bf16)ib[(long)(r0 + r) * C + (c0 + c)];
    }
    __syncthreads();
    for (int i = threadIdx.x; i < 4096; i += 256) {
        int c = i >> 6, r = i & 63;
        ob[(long)(c0 + c) * R + (r0 + r)] = t[r][c];
    }
}

// ---------------- merged bias folds: y_z = b2_z + W_z @ b1_z ----------------
__global__ __launch_bounds__(256) void k_bias_fold4(const float* __restrict__ W_in,
                                                    const float* __restrict__ Wa,
                                                    const float* __restrict__ bq,
                                                    const float* __restrict__ bk,
                                                    const float* __restrict__ bv,
                                                    const float* __restrict__ b_out,
                                                    const float* __restrict__ b_in,
                                                    const float* __restrict__ ba,
                                                    float* __restrict__ y) {
    int z = blockIdx.y;
    const float* W  = (z < 3) ? (W_in + (long)z * 1048576) : Wa;
    const float* b1 = (z == 0) ? bq : (z == 1) ? bk : (z == 2) ? bv : b_out;
    const float* b2 = (z < 3) ? (b_in + z * 1024) : ba;
    int row = blockIdx.x * 4 + (threadIdx.x >> 6);
    int lane = threadIdx.x & 63;
    const float* wr = W + (long)row * 1024;
    float s = 0.f;
    for (int k = lane; k < 1024; k += 64) s += wr[k] * b1[k];
#pragma unroll
    for (int o = 32; o >= 1; o >>= 1) s += __shfl_xor(s, o);
    if (lane == 0) y[z * 1024 + row] = b2[row] + s;
}

// ---------------- high-precision split-bf16 GEMM (register-prefetch pipeline) ----------------
enum { HP_SPLIT = 0, HP_F32 = 1, HP_SPLIT_HEADS = 2, HP_PROJ_QKV = 3 };

template<int MODE>
__global__ __launch_bounds__(256)
void gemm_hp(const bf16* __restrict__ Ah, const bf16* __restrict__ Al, int lda, long sAz,
             const bf16* __restrict__ Bh, const bf16* __restrict__ Bl, int ldb, long sBz,
             void* __restrict__ Chv, bf16* __restrict__ Cl, int ldc, long sCz,
             const float* __restrict__ bias, long sbz, float alpha, int M, int N, int K) {
    __shared__ alignas(16) bf16 sAh[128 * 32];
    __shared__ alignas(16) bf16 sAl[128 * 32];
    __shared__ alignas(16) bf16 sBh[128 * 32];
    __shared__ alignas(16) bf16 sBl[128 * 32];
    const int bm = blockIdx.y, bn = blockIdx.x, z = blockIdx.z;
    const int tid  = threadIdx.x;
    const int lane = tid & 63, wave = tid >> 6;
    const int quad = lane >> 4, l16 = lane & 15;
    const int wr = wave >> 1, wc = wave & 1;
    const int sr = tid >> 2;
    const int sc = (tid & 3) * 8;

    int arow0 = min(bm * 128 + sr, M - 1);
    int arow1 = min(bm * 128 + sr + 64, M - 1);
    int brow0 = min(bn * 128 + sr, N - 1);
    int brow1 = min(bn * 128 + sr + 64, N - 1);

    // HP_PROJ_QKV: z=0 uses A-slice 0 (Xq), z=1,2 use A-slice 1 (Xkv)
    const long zA = (MODE == HP_PROJ_QKV) ? (long)min(z, 1) : (long)z;
    const bf16* pAh0 = Ah + zA * sAz + (long)arow0 * lda + sc;
    const bf16* pAh1 = Ah + zA * sAz + (long)arow1 * lda + sc;
    const bf16* pAl0 = Al + zA * sAz + (long)arow0 * lda + sc;
    const bf16* pAl1 = Al + zA * sAz + (long)arow1 * lda + sc;
    const bf16* pBh0 = Bh + (long)z * sBz + (long)brow0 * ldb + sc;
    const bf16* pBh1 = Bh + (long)z * sBz + (long)brow1 * ldb + sc;
    const bf16* pBl0 = Bl + (long)z * sBz + (long)brow0 * ldb + sc;
    const bf16* pBl1 = Bl + (long)z * sBz + (long)brow1 * ldb + sc;
    const int wo = wave << 9;

    f32x4 acc[4][4];
#pragma unroll
    for (int i = 0; i < 4; i++)
#pragma unroll
        for (int j = 0; j < 4; j++) acc[i][j] = (f32x4){0.f, 0.f, 0.f, 0.f};

    // prologue: stage k=0
    ld16(sAh + wo,        pAh0);
    ld16(sAh + 2048 + wo, pAh1);
    ld16(sAl + wo,        pAl0);
    ld16(sAl + 2048 + wo, pAl1);
    ld16(sBh + wo,        pBh0);
    ld16(sBh + 2048 + wo, pBh1);
    ld16(sBl + wo,        pBl0);
    ld16(sBl + 2048 + wo, pBl1);
    __syncthreads();

    for (int k0 = 0; k0 < K; k0 += 32) {
        // read fragments of current tile into registers
        bf16x8 ah[4], al[4], bh[4], bl[4];
#pragma unroll
        for (int i = 0; i < 4; i++) {
            int ro = (wr * 64 + i * 16 + l16) * 32 + quad * 8;
            ah[i] = *(const bf16x8*)&sAh[ro];
            al[i] = *(const bf16x8*)&sAl[ro];
        }
#pragma unroll
        for (int j = 0; j < 4; j++) {
            int ro = (wc * 64 + j * 16 + l16) * 32 + quad * 8;
            bh[j] = *(const bf16x8*)&sBh[ro];
            bl[j] = *(const bf16x8*)&sBl[ro];
        }
        __syncthreads();   // all waves' reads complete -> safe to overwrite LDS
        int kn = k0 + 32;
        if (kn < K) {      // stage next tile; latency hides under the MFMAs below
            ld16(sAh + wo,        pAh0 + kn);
            ld16(sAh + 2048 + wo, pAh1 + kn);
            ld16(sAl + wo,        pAl0 + kn);
            ld16(sAl + 2048 + wo, pAl1 + kn);
            ld16(sBh + wo,        pBh0 + kn);
            ld16(sBh + 2048 + wo, pBh1 + kn);
            ld16(sBl + wo,        pBl0 + kn);
            ld16(sBl + 2048 + wo, pBl1 + kn);
        }
#pragma unroll
        for (int i = 0; i < 4; i++)
#pragma unroll
            for (int j = 0; j < 4; j++) {
                acc[i][j] = __builtin_amdgcn_mfma_f32_16x16x32_bf16(al[i], bh[j], acc[i][j], 0, 0, 0);
                acc[i][j] = __builtin_amdgcn_mfma_f32_16x16x32_bf16(ah[i], bl[j], acc[i][j], 0, 0, 0);
                acc[i][j] = __builtin_amdgcn_mfma_f32_16x16x32_bf16(ah[i], bh[j], acc[i][j], 0, 0, 0);
            }
        __syncthreads();   // implicit vmcnt(0): stage of kn complete
    }

#pragma unroll
    for (int i = 0; i < 4; i++) {
        int mbase = bm * 128 + wr * 64 + i * 16 + quad * 4;
#pragma unroll
        for (int j = 0; j < 4; j++) {
            int n = bn * 128 + wc * 64 + j * 16 + l16;
            if (n < N) {
                float bv = bias ? bias[(long)z * sbz + n] : 0.f;
#pragma unroll
                for (int r = 0; r < 4; r++) {
                    int m = mbase + r;
                    if (m < M) {
                        float v = alpha * acc[i][j][r] + bv;
                        if (MODE == HP_SPLIT) {
                            long cidx = (long)z * sCz + (long)m * ldc + n;
                            bf16 h = (bf16)v;
                            ((bf16*)Chv)[cidx] = h;
                            Cl[cidx] = (bf16)(v - (float)h);
                        } else if (MODE == HP_F32) {
                            long cidx = (long)z * sCz + (long)m * ldc + n;
                            ((float*)Chv)[cidx] = v;
                        } else if (MODE == HP_SPLIT_HEADS) {
                            int slice = ((m >> 10) << 4) + (n >> 6);
                            long idx = (long)z * sCz + (long)slice * 65536 + (long)(m & 1023) * 64 + (n & 63);
                            bf16 h = (bf16)v;
                            ((bf16*)Chv)[idx] = h;
                            Cl[idx] = (bf16)(v - (float)h);
                        } else {  // HP_PROJ_QKV: z<2 -> heads layout, z==2 -> token layout
                            long idx;
                            if (z < 2) {
                                int slice = ((m >> 10) << 4) + (n >> 6);
                                idx = (long)z * sCz + (long)slice * 65536 + (long)(m & 1023) * 64 + (n & 63);
                            } else {
                                idx = (long)z * sCz + (long)m * ldc + n;
                            }
                            bf16 h = (bf16)v;
                            ((bf16*)Chv)[idx] = h;
                            Cl[idx] = (bf16)(v - (float)h);
                        }
                    }
                }
            }
        }
    }
}

// ---------------- PV GEMM: double-buffered pipeline (1 block/CU regime) ----------------
__global__ __launch_bounds__(256)
void gemm_pv(const bf16* __restrict__ Ph, const bf16* __restrict__ Pl,
             const bf16* __restrict__ Vh, const bf16* __restrict__ Vl,
             bf16* __restrict__ Oh, bf16* __restrict__ Ol) {
    __shared__ alignas(16) bf16 sAh[2][128 * 32];
    __shared__ alignas(16) bf16 sAl[2][128 * 32];
    __shared__ alignas(16) bf16 sBh[2][64 * 32];
    __shared__ alignas(16) bf16 sBl[2][64 * 32];
    const int bm = blockIdx.x, z = blockIdx.y;
    const int tid = threadIdx.x, lane = tid & 63, wave = tid >> 6;
    const int quad = lane >> 4, l16 = lane & 15;
    const int wr = wave & 1, wc = wave >> 1;
    const int sr = tid >> 2, sc = (tid & 3) * 8;

    const bf16* pA0h = Ph + (long)z * 1048576 + (long)(bm * 128 + sr) * 1024 + sc;
    const bf16* pA1h = pA0h + 64 * 1024;
    const bf16* pA0l = Pl + (long)z * 1048576 + (long)(bm * 128 + sr) * 1024 + sc;
    const bf16* pA1l = pA0l + 64 * 1024;
    const bf16* pB0h = Vh + (long)z * 65536 + (long)sr * 1024 + sc;
    const bf16* pB0l = Vl + (long)z * 65536 + (long)sr * 1024 + sc;
    const int wo = wave << 9;

    f32x4 acc[4][2];
#pragma unroll
    for (int i = 0; i < 4; i++)
#pragma unroll
        for (int j = 0; j < 2; j++) acc[i][j] = (f32x4){0.f, 0.f, 0.f, 0.f};

    // prologue: stage tile 0 into buf 0
    ld16(sAh[0] + wo,        pA0h);
    ld16(sAh[0] + 2048 + wo, pA1h);
    ld16(sAl[0] + wo,        pA0l);
    ld16(sAl[0] + 2048 + wo, pA1l);
    ld16(sBh[0] + wo, pB0h);
    ld16(sBl[0] + wo, pB0l);
    __syncthreads();

    int cur = 0;
    for (int k0 = 0; k0 < 1024; k0 += 32) {
        int kn = k0 + 32;
        if (kn < 1024) {   // stage next tile into other buffer
            ld16(sAh[cur ^ 1] + wo,        pA0h + kn);
            ld16(sAh[cur ^ 1] + 2048 + wo, pA1h + kn);
            ld16(sAl[cur ^ 1] + wo,        pA0l + kn);
            ld16(sAl[cur ^ 1] + 2048 + wo, pA1l + kn);
            ld16(sBh[cur ^ 1] + wo, pB0h + kn);
            ld16(sBl[cur ^ 1] + wo, pB0l + kn);
        }
        const bf16* cAh = sAh[cur]; const bf16* cAl = sAl[cur];
        const bf16* cBh = sBh[cur]; const bf16* cBl = sBl[cur];
        bf16x8 ah[4], al[4], bh[2], bl[2];
#pragma unroll
        for (int i = 0; i < 4; i++) {
            int ro = (wr * 64 + i * 16 + l16) * 32 + quad * 8;
            ah[i] = *(const bf16x8*)&cAh[ro];
            al[i] = *(const bf16x8*)&cAl[ro];
        }
#pragma unroll
        for (int j = 0; j < 2; j++) {
            int ro = (wc * 32 + j * 16 + l16) * 32 + quad * 8;
            bh[j] = *(const bf16x8*)&cBh[ro];
            bl[j] = *(const bf16x8*)&cBl[ro];
        }
#pragma unroll
        for (int i = 0; i < 4; i++)
#pragma unroll
            for (int j = 0; j < 2; j++) {
                acc[i][j] = __builtin_amdgcn_mfma_f32_16x16x32_bf16(al[i], bh[j], acc[i][j], 0, 0, 0);
                acc[i][j] = __builtin_amdgcn_mfma_f32_16x16x32_bf16(ah[i], bl[j], acc[i][j], 0, 0, 0);
                acc[i][j] = __builtin_amdgcn_mfma_f32_16x16x32_bf16(ah[i], bh[j], acc[i][j], 0, 0, 0);
            }
        __syncthreads();   // stage done (vmcnt0) + all reads of cur done
        cur ^= 1;
    }

#pragma unroll
    for (int i = 0; i < 4; i++) {
        int mbase = bm * 128 + wr * 64 + i * 16 + quad * 4;
#pragma unroll
        for (int j = 0; j < 2; j++) {
            int n = wc * 32 + j * 16 + l16;
#pragma unroll
            for (int r = 0; r < 4; r++) {
                int m = mbase + r;
                long idx = (long)z * 65536 + (long)m * 64 + n;
                float v = acc[i][j][r];
                bf16 h = (bf16)v;
                Oh[idx] = h;
                Ol[idx] = (bf16)(v - (float)h);
            }
        }
    }
}

// ---------------- MoE GEMM1 (compacted tile grid, single-buffer 2-barrier, GELU) ----------------
__global__ __launch_bounds__(256)
void gemm_moe1(const bf16* __restrict__ Ae, const bf16* __restrict__ ew1t,
               const float* __restrict__ eb1, bf16* __restrict__ Hp,
               const int* __restrict__ counts, const int* __restrict__ bases,
               const int* __restrict__ tiles, const int* __restrict__ ntile) {
    const int wg = xcd_swz(blockIdx.x, gridDim.x);
    const int tile = wg >> 5;
    const int bn = wg & 31;
    if (tile >= ntile[0]) return;
    const int te = tiles[tile];
    const int e = te >> 16, bm = te & 0xffff;
    const int M = counts[e];
    const bf16* A = Ae + (long)bases[e] * 1024;
    const bf16* B = ew1t + (long)e * 4194304;
    bf16* C = Hp + (long)bases[e] * 4096;
    const float* bias = eb1 + e * 4096;

    __shared__ alignas(16) bf16 sA[128 * 32];
    __shared__ alignas(16) bf16 sB[128 * 32];
    const int tid  = threadIdx.x;
    const int lane = tid & 63, wave = tid >> 6;
    const int quad = lane >> 4, l16 = lane & 15;
    const int wr = wave >> 1, wc = wave & 1;
    const int sr = tid >> 2;
    const int sc = (tid & 3) * 8;

    int arow0 = min(bm * 128 + sr, M - 1);
    int arow1 = min(bm * 128 + sr + 64, M - 1);
    int brow0 = bn * 128 + sr;
    const bf16* pA0 = A + (long)arow0 * 1024 + sc;
    const bf16* pA1 = A + (long)arow1 * 1024 + sc;
    const bf16* pB0 = B + (long)brow0 * 1024 + sc;
    const bf16* pB1 = B + (long)(brow0 + 64) * 1024 + sc;
    const int wo = wave << 9;

    f32x4 acc[4][4];
#pragma unroll
    for (int i = 0; i < 4; i++)
#pragma unroll
        for (int j = 0; j < 4; j++) acc[i][j] = (f32x4){0.f, 0.f, 0.f, 0.f};

    for (int k0 = 0; k0 < 1024; k0 += 32) {
        __syncthreads();
        ld16(sA + wo,        pA0 + k0);
        ld16(sA + 2048 + wo, pA1 + k0);
        ld16(sB + wo,        pB0 + k0);
        ld16(sB + 2048 + wo, pB1 + k0);
        __syncthreads();
        bf16x8 af[4], bfr[4];
#pragma unroll
        for (int i = 0; i < 4; i++)
            af[i] = *(const bf16x8*)&sA[(wr * 64 + i * 16 + l16) * 32 + quad * 8];
#pragma unroll
        for (int j = 0; j < 4; j++)
            bfr[j] = *(const bf16x8*)&sB[(wc * 64 + j * 16 + l16) * 32 + quad * 8];
#pragma unroll
        for (int i = 0; i < 4; i++)
#pragma unroll
            for (int j = 0; j < 4; j++)
                acc[i][j] = __builtin_amdgcn_mfma_f32_16x16x32_bf16(af[i], bfr[j], acc[i][j], 0, 0, 0);
    }

#pragma unroll
    for (int i = 0; i < 4; i++) {
        int mbase = bm * 128 + wr * 64 + i * 16 + quad * 4;
#pragma unroll
        for (int j = 0; j < 4; j++) {
            int n = bn * 128 + wc * 64 + j * 16 + l16;
            float bv = bias[n];
#pragma unroll
            for (int r = 0; r < 4; r++) {
                int m = mbase + r;
                if (m < M) {
                    float v = acc[i][j][r] + bv;
                    float g = 0.5f * v * (1.f + erff(v * 0.70710678118654752f));
                    C[(long)m * 4096 + n] = (bf16)g;
                }
            }
        }
    }
}

// ---------------- MoE GEMM2 (compacted tile grid, single-buffer 2-barrier, fp32 out) ----------------
__global__ __launch_bounds__(256)
void gemm_moe2(const bf16* __restrict__ Hp, const bf16* __restrict__ ew2t,
               float* __restrict__ Y,
               const int* __restrict__ counts, const int* __restrict__ bases,
               const int* __restrict__ tiles, const int* __restrict__ ntile) {
    const int wg = xcd_swz(blockIdx.x, gridDim.x);
    const int tile = wg >> 3;
    const int bn = wg & 7;
    if (tile >= ntile[0]) return;
    const int te = tiles[tile];
    const int e = te >> 16, bm = te & 0xffff;
    const int M = counts[e];
    const bf16* A = Hp + (long)bases[e] * 4096;
    const bf16* B = ew2t + (long)e * 4194304;
    float* C = Y + (long)bases[e] * 1024;

    __shared__ alignas(16) bf16 sA[128 * 32];
    __shared__ alignas(16) bf16 sB[128 * 32];
    const int tid  = threadIdx.x;
    const int lane = tid & 63, wave = tid >> 6;
    const int quad = lane >> 4, l16 = lane & 15;
    const int wr = wave >> 1, wc = wave & 1;
    const int sr = tid >> 2;
    const int sc = (tid & 3) * 8;

    int arow0 = min(bm * 128 + sr, M - 1);
    int arow1 = min(bm * 128 + sr + 64, M - 1);
    int brow0 = bn * 128 + sr;
    const bf16* pA0 = A + (long)arow0 * 4096 + sc;
    const bf16* pA1 = A + (long)arow1 * 4096 + sc;
    const bf16* pB0 = B + (long)brow0 * 4096 + sc;
    const bf16* pB1 = B + (long)(brow0 + 64) * 4096 + sc;
    const int wo = wave << 9;

    f32x4 acc[4][4];
#pragma unroll
    for (int i = 0; i < 4; i++)
#pragma unroll
        for (int j = 0; j < 4; j++) acc[i][j] = (f32x4){0.f, 0.f, 0.f, 0.f};

    for (int k0 = 0; k0 < 4096; k0 += 32) {
        __syncthreads();
        ld16(sA + wo,        pA0 + k0);
        ld16(sA + 2048 + wo, pA1 + k0);
        ld16(sB + wo,        pB0 + k0);
        ld16(sB + 2048 + wo, pB1 + k0);
        __syncthreads();
        bf16x8 af[4], bfr[4];
#pragma unroll
        for (int i = 0; i < 4; i++)
            af[i] = *(const bf16x8*)&sA[(wr * 64 + i * 16 + l16) * 32 + quad * 8];
#pragma unroll
        for (int j = 0; j < 4; j++)
            bfr[j] = *(const bf16x8*)&sB[(wc * 64 + j * 16 + l16) * 32 + quad * 8];
#pragma unroll
        for (int i = 0; i < 4; i++)
#pragma unroll
            for (int j = 0; j < 4; j++)
                acc[i][j] = __builtin_amdgcn_mfma_f32_16x16x32_bf16(af[i], bfr[j], acc[i][j], 0, 0, 0);
    }

#pragma unroll
    for (int i = 0; i < 4; i++) {
        int mbase = bm * 128 + wr * 64 + i * 16 + quad * 4;
#pragma unroll
        for (int j = 0; j < 4; j++) {
            int n = bn * 128 + wc * 64 + j * 16 + l16;
#pragma unroll
            for (int r = 0; r < 4; r++) {
                int m = mbase + r;
                if (m < M) C[(long)m * 1024 + n] = acc[i][j][r];
            }
        }
    }
}

// ---------------- per-slice V transpose ----------------
__global__ __launch_bounds__(256) void k_vsplit(const bf16* __restrict__ VH_h,
                                                const bf16* __restrict__ VH_l,
                                                bf16* __restrict__ VT_h,
                                                bf16* __restrict__ VT_l) {
    __shared__ bf16 th[64][65];
    __shared__ bf16 tl[64][65];
    int s = blockIdx.y, q0 = blockIdx.x * 64;
    int b = s >> 4, h = s & 15;
    long ibase = ((long)(b * 1024 + q0)) * 1024 + h * 64;
    for (int i = threadIdx.x; i < 4096; i += 256) {
        int q = i >> 6, d = i & 63;
        th[q][d] = VH_h[ibase + (long)q * 1024 + d];
        tl[q][d] = VH_l[ibase + (long)q * 1024 + d];
    }
    __syncthreads();
    long obase = (long)s * 65536 + q0;
    for (int i = threadIdx.x; i < 4096; i += 256) {
        int d = i >> 6, q = i & 63;
        VT_h[obase + (long)d * 1024 + q] = th[q][d];
        VT_l[obase + (long)d * 1024 + q] = tl[q][d];
    }
}

// ---------------- O reassembly ----------------
__global__ __launch_bounds__(256) void k_ocopy(const bf16* __restrict__ Op_h,
                                               const bf16* __restrict__ Op_l,
                                               bf16* __restrict__ O_h,
                                               bf16* __restrict__ O_l) {
    int t = blockIdx.x * 4 + (threadIdx.x >> 6);
    int lane = threadIdx.x & 63;
    int b = t >> 10, q = t & 1023;
    int h = lane >> 2, dd = (lane & 3) * 16;
    long src = ((long)(b * 16 + h)) * 65536 + (long)q * 64 + dd;
    long dst = (long)t * 1024 + h * 64 + dd;
    *(bf16x8*)(O_h + dst)     = *(const bf16x8*)(Op_h + src);
    *(bf16x8*)(O_h + dst + 8) = *(const bf16x8*)(Op_h + src + 8);
    *(bf16x8*)(O_l + dst)     = *(const bf16x8*)(Op_l + src);
    *(bf16x8*)(O_l + dst + 8) = *(const bf16x8*)(Op_l + src + 8);
}

// ---------------- gather expert rows (packed) ----------------
__global__ __launch_bounds__(256) void k_gather(const bf16* __restrict__ Xb,
                                                const int* __restrict__ tok,
                                                const int* __restrict__ counts,
                                                const int* __restrict__ bases,
                                                bf16* __restrict__ Ae) {
    int e = blockIdx.y;
    int cnt = counts[e];
    long base = bases[e];
    for (int i = blockIdx.x; i < cnt; i += gridDim.x) {
        int t = tok[e * 4096 + i];
        const bf16x4* src = (const bf16x4*)(Xb + (long)t * 1024);
        bf16x4* dst = (bf16x4*)(Ae + (base + i) * 1024);
        dst[threadIdx.x] = src[threadIdx.x];
    }
}

// ---------------- in-place softmax on split rows ----------------
__global__ __launch_bounds__(256) void k_softmax_ip(bf16* __restrict__ Sh,
                                                    bf16* __restrict__ Sl) {
    int row = blockIdx.x * 4 + (threadIdx.x >> 6);
    int lane = threadIdx.x & 63;
    long o = (long)row * 1024 + lane * 16;
    bf16x8 h0 = *(const bf16x8*)(Sh + o), h1 = *(const bf16x8*)(Sh + o + 8);
    bf16x8 l0 = *(const bf16x8*)(Sl + o), l1 = *(const bf16x8*)(Sl + o + 8);
    float v[16];
#pragma unroll
    for (int i = 0; i < 8; i++) {
        v[i] = (float)h0[i] + (float)l0[i];
        v[8 + i] = (float)h1[i] + (float)l1[i];
    }
    float mx = v[0];
#pragma unroll
    for (int i = 1; i < 16; i++) mx = fmaxf(mx, v[i]);
#pragma unroll
    for (int of = 32; of >= 1; of >>= 1) mx = fmaxf(mx, __shfl_xor(mx, of));
    float s = 0.f;
#pragma unroll
    for (int i = 0; i < 16; i++) { v[i] = expf(v[i] - mx); s += v[i]; }
#pragma unroll
    for (int of = 32; of >= 1; of >>= 1) s += __shfl_xor(s, of);
    float inv = 1.f / s;
#pragma unroll
    for (int i = 0; i < 8; i++) {
        float a = v[i] * inv;
        h0[i] = (bf16)a; l0[i] = (bf16)(a - (float)h0[i]);
        float b = v[8 + i] * inv;
        h1[i] = (bf16)b; l1[i] = (bf16)(b - (float)h1[i]);
    }
    *(bf16x8*)(Sh + o) = h0;  *(bf16x8*)(Sh + o + 8) = h1;
    *(bf16x8*)(Sl + o) = l0;  *(bf16x8*)(Sl + o + 8) = l1;
}

// ---------------- layernorm ----------------
__global__ __launch_bounds__(256) void k_ln(const float* __restrict__ xin,
                                            const float* __restrict__ resid,
                                            const float* __restrict__ g,
                                            const float* __restrict__ bb,
                                            float* __restrict__ outf,
                                            bf16* __restrict__ outb) {
    int row = blockIdx.x * 4 + (threadIdx.x >> 6);
    int lane = threadIdx.x & 63;
    long base = (long)row * 1024 + lane * 16;
    float v[16];
#pragma unroll
    for (int i = 0; i < 16; i += 4) {
        f32x4 a = *(const f32x4*)(xin + base + i);
        if (resid) { f32x4 r4 = *(const f32x4*)(resid + base + i); a += r4; }
        v[i] = a[0]; v[i + 1] = a[1]; v[i + 2] = a[2]; v[i + 3] = a[3];
    }
    float s = 0.f;
#pragma unroll
    for (int i = 0; i < 16; i++) s += v[i];
#pragma unroll
    for (int o = 32; o >= 1; o >>= 1) s += __shfl_xor(s, o);
    float mean = s * (1.f / 1024.f);
    float vs = 0.f;
#pragma unroll
    for (int i = 0; i < 16; i++) { float d = v[i] - mean; vs += d * d; }
#pragma unroll
    for (int o = 32; o >= 1; o >>= 1) vs += __shfl_xor(vs, o);
    float inv = 1.f / sqrtf(vs * (1.f / 1024.f) + 1e-5f);
    const float* gp = g + lane * 16;
    const float* bp = bb + lane * 16;
#pragma unroll
    for (int i = 0; i < 16; i++) {
        float o = (v[i] - mean) * inv * gp[i] + bp[i];
        if (outf) outf[base + i] = o;
        if (outb) outb[base + i] = (bf16)o;
    }
}

// ---------------- fused MoE combine + residual + LN2 ----------------
__global__ __launch_bounds__(256) void k_moe_ln(const float* __restrict__ Y,
                                                const int* __restrict__ pos,
                                                const int* __restrict__ bases,
                                                const float* __restrict__ combine,
                                                const float* __restrict__ eb2,
                                                const float* __restrict__ resid,
                                                const float* __restrict__ g,
                                                const float* __restrict__ bb,
                                                float* __restrict__ outf) {
    int row = blockIdx.x * 4 + (threadIdx.x >> 6);
    int lane = threadIdx.x & 63;
    long base = (long)row * 1024 + lane * 16;
    float v[16];
#pragma unroll
    for (int i = 0; i < 16; i += 4) {
        f32x4 a = *(const f32x4*)(resid + base + i);
        v[i] = a[0]; v[i + 1] = a[1]; v[i + 2] = a[2]; v[i + 3] = a[3];
    }
    for (int e = 0; e < 8; e++) {
        int p = pos[row * 8 + e];
        if (p >= 0) {
            float c = combine[row * 8 + e];
            const float* yr = Y + (long)(bases[e] + p) * 1024 + lane * 16;
            const float* br = eb2 + e * 1024 + lane * 16;
#pragma unroll
            for (int i = 0; i < 16; i += 4) {
                f32x4 y4 = *(const f32x4*)(yr + i);
                f32x4 b4 = *(const f32x4*)(br + i);
                v[i]     += c * (y4[0] + b4[0]);
                v[i + 1] += c * (y4[1] + b4[1]);
                v[i + 2] += c * (y4[2] + b4[2]);
                v[i + 3] += c * (y4[3] + b4[3]);
            }
        }
    }
    float s = 0.f;
#pragma unroll
    for (int i = 0; i < 16; i++) s += v[i];
#pragma unroll
    for (int o = 32; o >= 1; o >>= 1) s += __shfl_xor(s, o);
    float mean = s * (1.f / 1024.f);
    float vs = 0.f;
#pragma unroll
    for (int i = 0; i < 16; i++) { float d = v[i] - mean; vs += d * d; }
#pragma unroll
    for (int o = 32; o >= 1; o >>= 1) vs += __shfl_xor(vs, o);
    float inv = 1.f / sqrtf(vs * (1.f / 1024.f) + 1e-5f);
    const float* gp = g + lane * 16;
    const float* bp = bb + lane * 16;
#pragma unroll
    for (int i = 0; i < 16; i++)
        outf[base + i] = (v[i] - mean) * inv * gp[i] + bp[i];
}

// ---------------- gating (no routing atomics) ----------------
__global__ __launch_bounds__(256) void k_gate(const float* __restrict__ X,
                                              const float* __restrict__ Wg,
                                              float* __restrict__ combine,
                                              float* __restrict__ partials) {
    __shared__ float sm[16];
    if (threadIdx.x < 16) sm[threadIdx.x] = 0.f;
    __syncthreads();
    int t = blockIdx.x * 4 + (threadIdx.x >> 6);
    int lane = threadIdx.x & 63;
    const float* x = X + (long)t * 1024;
    float acc[8] = {0.f, 0.f, 0.f, 0.f, 0.f, 0.f, 0.f, 0.f};
    for (int i = lane; i < 1024; i += 64) {
        float xv = x[i];
        const float* w = Wg + i * 8;
#pragma unroll
        for (int e = 0; e < 8; e++) acc[e] += xv * w[e];
    }
#pragma unroll
    for (int e = 0; e < 8; e++)
#pragma unroll
        for (int o = 32; o >= 1; o >>= 1) acc[e] += __shfl_xor(acc[e], o);
    if (lane == 0) {
        float mx = acc[0];
#pragma unroll
        for (int e = 1; e < 8; e++) mx = fmaxf(mx, acc[e]);
        float p[8], s = 0.f;
#pragma unroll
        for (int e = 0; e < 8; e++) { p[e] = expf(acc[e] - mx); s += p[e]; }
        float invs = 1.f / s;
#pragma unroll
        for (int e = 0; e < 8; e++) p[e] *= invs;
        float b1 = -1.f, b2 = -1.f, b3 = -1.f; int i1 = 0, i2 = 0, i3 = 0;
#pragma unroll
        for (int e = 0; e < 8; e++) {
            float pe = p[e];
            if (pe > b1)      { b3 = b2; i3 = i2; b2 = b1; i2 = i1; b1 = pe; i1 = e; }
            else if (pe > b2) { b3 = b2; i3 = i2; b2 = pe; i2 = e; }
            else if (pe > b3) { b3 = pe; i3 = e; }
        }
        float c[8] = {0.f, 0.f, 0.f, 0.f, 0.f, 0.f, 0.f, 0.f};
        c[i1] = b1;
        if (b2 >= THRESH_C) c[i2] = b2;
        if (b3 >= THRESH_C) c[i3] = b3;
        float* co = combine + (long)t * 8;
#pragma unroll
        for (int e = 0; e < 8; e++) co[e] = c[e];
#pragma unroll
        for (int e = 0; e < 8; e++) {
            atomicAdd(&sm[e], p[e]);
            if (c[e] > 0.f) atomicAdd(&sm[8 + e], 1.f);
        }
    }
    __syncthreads();
    if (threadIdx.x < 16) partials[(long)blockIdx.x * 16 + threadIdx.x] = sm[threadIdx.x];
}

// ---------------- routing: per-expert parallel scan (8 blocks) ----------------
__global__ __launch_bounds__(256) void k_route_e(const float* __restrict__ combine,
                                                 int* __restrict__ counts,
                                                 int* __restrict__ tok,
                                                 int* __restrict__ pos) {
    __shared__ int scan[256];
    int e = blockIdx.x;
    int tid = threadIdx.x;
    int pred[16]; int cnt = 0;
#pragma unroll
    for (int j = 0; j < 16; j++) {
        int t = tid * 16 + j;
        pred[j] = combine[t * 8 + e] > 0.f ? 1 : 0;
        cnt += pred[j];
    }
    scan[tid] = cnt;
    __syncthreads();
    for (int off = 1; off < 256; off <<= 1) {
        int v = (tid >= off) ? scan[tid - off] : 0;
        __syncthreads();
        scan[tid] += v;
        __syncthreads();
    }
    int start = scan[tid] - cnt;
    int o = e * 4096 + start;
    int gp = start;                 // expert-relative position
#pragma unroll
    for (int j = 0; j < 16; j++) {
        int t = tid * 16 + j;
        if (pred[j]) { tok[o++] = t; pos[t * 8 + e] = gp++; }
        else pos[t * 8 + e] = -1;
    }
    if (tid == 0) counts[e] = scan[255];
}

// ---------------- routing finalize: bases + tile list (trivial) ----------------
__global__ __launch_bounds__(64) void k_route_fin(const int* __restrict__ counts,
                                                  int* __restrict__ bases,
                                                  int* __restrict__ tiles,
                                                  int* __restrict__ ntile) {
    if (threadIdx.x == 0) {
        int b = 0, nt = 0;
        for (int e = 0; e < 8; e++) {
            bases[e] = b;
            int nte = (counts[e] + 127) >> 7;
            for (int bb = 0; bb < nte; bb++) tiles[nt++] = (e << 16) | bb;
            b += counts[e];
        }
        ntile[0] = nt;
    }
}

// ---------------- aux reduce ----------------
__global__ __launch_bounds__(256) void k_aux(const float* __restrict__ partials, int nblocks,
                                             float* __restrict__ auxout) {
    __shared__ float red[256];
    int tid = threadIdx.x;
    int e = tid & 15, grp = tid >> 4;
    float s = 0.f;
    for (int b = grp; b < nblocks; b += 16) s += partials[(long)b * 16 + e];
    red[tid] = s;
    __syncthreads();
    if (grp == 0) {
        float tot = 0.f;
        for (int g2 = 0; g2 < 16; g2++) tot += red[g2 * 16 + e];
        red[tid] = tot;
    }
    __syncthreads();
    if (tid == 0) {
        float s2 = 0.f;
        for (int e2 = 0; e2 < 8; e2++)
            s2 += (red[8 + e2] * (1.f / 4096.f)) * (red[e2] * (1.f / 4096.f));
        auxout[0] = COEF_C * 8.f * s2;
    }
}

// ---------------- host ----------------
extern "C" void kernel_launch(void* const* d_in, const int* in_sizes, int n_in,
                              void* d_out, int out_size, void* d_ws, size_t ws_size,
                              hipStream_t stream) {
    const float* query     = (const float*)d_in[0];
    const float* key_value = (const float*)d_in[1];
    const float* Wq   = (const float*)d_in[2];
    const float* bq   = (const float*)d_in[3];
    const float* Wk   = (const float*)d_in[4];
    const float* bk   = (const float*)d_in[5];
    const float* Wv   = (const float*)d_in[6];
    const float* bv   = (const float*)d_in[7];
    const float* W_in = (const float*)d_in[8];
    const float* b_in = (const float*)d_in[9];
    const float* W_out = (const float*)d_in[10];
    const float* b_out = (const float*)d_in[11];
    const float* Wa   = (const float*)d_in[12];
    const float* ba   = (const float*)d_in[13];
    const float* ln1_g = (const float*)d_in[14];
    const float* ln1_b = (const float*)d_in[15];
    const float* Wg   = (const float*)d_in[16];
    const float* ew1  = (const float*)d_in[17];
    const float* eb1  = (const float*)d_in[18];
    const float* ew2  = (const float*)d_in[19];
    const float* eb2  = (const float*)d_in[20];
    const float* ln2_g = (const float*)d_in[21];
    const float* ln2_b = (const float*)d_in[22];

    const size_t MBY = 1ull << 20;
    const long MB1 = 1024L * 1024L;
    char* ws = (char*)d_ws;

    bf16* Sh   = (bf16*)(ws + 0 * MBY);
    bf16* Sl   = (bf16*)(ws + 64 * MBY);
    bf16* ew1t = (bf16*)(ws + 0 * MBY);
    bf16* ew2t = (bf16*)(ws + 64 * MBY);
    bf16* WAll_h = (bf16*)(ws + 128 * MBY);
    bf16* WAll_l = (bf16*)(ws + 136 * MBY);
    bf16* WT_h   = (bf16*)(ws + 144 * MBY);
    bf16* WT_l   = (bf16*)(ws + 152 * MBY);
    bf16* Xq_h  = (bf16*)(ws + 160 * MBY), *Xq_l  = (bf16*)(ws + 168 * MBY);
    bf16* Xkv_h = (bf16*)(ws + 176 * MBY), *Xkv_l = (bf16*)(ws + 184 * MBY);
    bf16* O_h  = (bf16*)(ws + 160 * MBY), *O_l  = (bf16*)(ws + 168 * MBY);
    bf16* QHp_h = (bf16*)(ws + 192 * MBY), *QHp_l = (bf16*)(ws + 200 * MBY);
    bf16* KHp_h = (bf16*)(ws + 208 * MBY), *KHp_l = (bf16*)(ws + 216 * MBY);
    bf16* VH_h  = (bf16*)(ws + 224 * MBY), *VH_l  = (bf16*)(ws + 232 * MBY);
    bf16* VTp_h = (bf16*)(ws + 240 * MBY), *VTp_l = (bf16*)(ws + 248 * MBY);
    bf16* Op_h  = (bf16*)(ws + 256 * MBY), *Op_l  = (bf16*)(ws + 264 * MBY);
    float* Xf   = (float*)(ws + 256 * MBY);
    float* Af   = (float*)(ws + 272 * MBY);
    bf16* Ae      = (bf16*)(ws + 128 * MBY);
    bf16* Hp      = (bf16*)(ws + 152 * MBY);
    float* Yp     = (float*)(ws + 272 * MBY);
    bf16* Xb   = (bf16*)(ws + 320 * MBY);
    bf16* Weff_h = (bf16*)(ws + 328 * MBY);
    bf16* Weff_l = (bf16*)(ws + 336 * MBY);
    float* combine  = (float*)(ws + 344 * MBY);
    float* partials = (float*)(ws + 344 * MBY + 128 * 1024);
    float* beff     = (float*)(ws + 344 * MBY + 192 * 1024);
    int*   counts   = (int*)  (ws + 344 * MBY + 212 * 1024);
    int*   bases    = (int*)  (ws + 344 * MBY + 213 * 1024);
    int*   tok      = (int*)  (ws + 344 * MBY + 214 * 1024);
    int*   pos      = (int*)  (ws + 344 * MBY + 342 * 1024);
    int*   tiles    = (int*)  (ws + 344 * MBY + 472 * 1024);
    int*   ntile    = tiles + 128;

    dim3 blk(256);

    // ---- prep ----
    k_f32_to_split<<<4096, blk, 0, stream>>>(query, Xq_h, Xq_l, 4L * MB1);
    k_f32_to_split<<<4096, blk, 0, stream>>>(key_value, Xkv_h, Xkv_l, 4L * MB1);
    k_f32_to_split<<<3072, blk, 0, stream>>>(W_in, WAll_h, WAll_l, 3L * MB1);
    k_f32_to_split<<<1024, blk, 0, stream>>>(Wa, WAll_h + 3 * MB1, WAll_l + 3 * MB1, MB1);
    k_transpose4_split<<<dim3(16, 16, 4), blk, 0, stream>>>(Wq, Wk, Wv, W_out, WT_h, WT_l);
    k_bias_fold4<<<dim3(256, 4), blk, 0, stream>>>(W_in, Wa, bq, bk, bv, b_out, b_in, ba, beff);

    // ---- weight folds ----
    gemm_hp<HP_SPLIT><<<dim3(8, 8, 4), blk, 0, stream>>>(
        WAll_h, WAll_l, 1024, MB1, WT_h, WT_l, 1024, MB1,
        Weff_h, Weff_l, 1024, MB1, nullptr, 0, 1.f, 1024, 1024, 1024);

    // ---- projections: Q+K+V merged (z=3, 768 blocks = 3/CU) ----
    gemm_hp<HP_PROJ_QKV><<<dim3(8, 32, 3), blk, 0, stream>>>(
        Xq_h, Xq_l, 1024, 8 * MB1, Weff_h, Weff_l, 1024, MB1,
        QHp_h, QHp_l, 1024, 8 * MB1, beff, 1024, 1.f, 4096, 1024, 1024);
    k_vsplit<<<dim3(16, 64), blk, 0, stream>>>(VH_h, VH_l, VTp_h, VTp_l);

    // ---- attention: 2 halves of 32 (b,h) slices ----
    for (int half = 0; half < 2; half++) {
        long so = (long)half * 32 * 65536;
        gemm_hp<HP_SPLIT><<<dim3(8, 8, 32), blk, 0, stream>>>(
            QHp_h + so, QHp_l + so, 64, 65536,
            KHp_h + so, KHp_l + so, 64, 65536,
            Sh, Sl, 1024, MB1, nullptr, 0, 0.125f, 1024, 1024, 64);
        k_softmax_ip<<<8192, blk, 0, stream>>>(Sh, Sl);
        gemm_pv<<<dim3(8, 32), blk, 0, stream>>>(Sh, Sl, VTp_h + so, VTp_l + so,
                                                 Op_h + so, Op_l + so);
    }
    k_ocopy<<<1024, blk, 0, stream>>>(Op_h, Op_l, O_h, O_l);

    // ---- out-proj+adapter (folded) + LN1 + gate + route ----
    gemm_hp<HP_F32><<<dim3(8, 32, 1), blk, 0, stream>>>(
        O_h, O_l, 1024, 0, Weff_h + 3 * MB1, Weff_l + 3 * MB1, 1024, 0,
        Af, nullptr, 1024, 0, beff + 3072, 0, 1.f, 4096, 1024, 1024);
    k_ln<<<1024, blk, 0, stream>>>(Af, query, ln1_g, ln1_b, Xf, Xb);
    k_gate<<<1024, blk, 0, stream>>>(Xf, Wg, combine, partials);
    k_route_e<<<8, blk, 0, stream>>>(combine, counts, tok, pos);
    k_route_fin<<<1, 64, 0, stream>>>(counts, bases, tiles, ntile);
    k_gather<<<dim3(512, 8), blk, 0, stream>>>(Xb, tok, counts, bases, Ae);

    // ---- expert weight transposes ----
    k_transpose_ew<<<dim3(64, 16, 8), blk, 0, stream>>>(ew1, ew1t, 1024, 4096);
    k_transpose_ew<<<dim3(16, 64, 8), blk, 0, stream>>>(ew2, ew2t, 4096, 1024);

    // ---- batched routed MoE ----
    gemm_moe1<<<dim3(104 * 32), blk, 0, stream>>>(Ae, ew1t, eb1, Hp, counts, bases, tiles, ntile);
    gemm_moe2<<<dim3(104 * 8), blk, 0, stream>>>(Hp, ew2t, Yp, counts, bases, tiles, ntile);

    // ---- fused MoE combine + residual + LN2, then aux ----
    k_moe_ln<<<1024, blk, 0, stream>>>(Yp, pos, bases, combine, eb2, Xf, ln2_g, ln2_b, (float*)d_out);
    k_aux<<<1, blk, 0, stream>>>(partials, 1024, (float*)d_out + (out_size - 1));
}